// Round 1
// baseline (218.969 us; speedup 1.0000x reference)
//
#include <hip/hip_runtime.h>
#include <math.h>

#define TT 256
#define WARM 16
// ws float offsets (chain outputs + scan intermediates only)
#define OFF_K    5632   // 17 x 512 -> 14336
#define OFF_MC   14336  // 17 x 256 -> 18688
#define OFF_NB   18688  // 17 x 128 -> 20864
#define OFF_P0   20864  // Mseg0 (256) -> 21120
#define OFF_PP   21120  // Mc16^16 (256) -> 21376
#define OFF_WSEG 21376  // 16 x 256 x 16 -> 86912
#define OFF_BND  86912  // 16 x 256 x 16 -> 152448
#define NEED_WS_BYTES ((size_t)152448 * 4)

__device__ __forceinline__ float softplus(float v) {
    return fmaxf(v, 0.0f) + log1pf(expf(-fabsf(v)));
}

// Shuffle-based Gauss-Jordan, [X|I] -> [I|X^-1] (verified R5-R12).
// Layout: lane (i, gq) holds aug[i][8*gq+k], k=0..7.
__device__ __forceinline__ void gj16(float (&aug)[8], const int i, const int gq) {
#pragma unroll
    for (int j = 0; j < 16; ++j) {
        float prow[8];
#pragma unroll
        for (int k = 0; k < 8; ++k) prow[k] = __shfl(aug[k], j + 16 * gq);
        const float pjj = __shfl(aug[j & 7], j + 16 * (j >> 3));
        const float cij = __shfl(aug[j & 7], i + 16 * (j >> 3));
        const float pivinv = 1.0f / pjj;
        const float f = cij * pivinv;
#pragma unroll
        for (int k = 0; k < 8; ++k)
            aug[k] = (i == j) ? prow[k] * pivinv : aug[k] - f * prow[k];
    }
}

// Load a full 16-float row from a stride-20 LDS matrix into registers (4x b128).
#define LD_ROW16(Mt, r, row) do { \
    const float4 r0_ = *(const float4*)&Mt[r][0]; \
    const float4 r1_ = *(const float4*)&Mt[r][4]; \
    const float4 r2_ = *(const float4*)&Mt[r][8]; \
    const float4 r3_ = *(const float4*)&Mt[r][12]; \
    row[0]=r0_.x;  row[1]=r0_.y;  row[2]=r0_.z;  row[3]=r0_.w; \
    row[4]=r1_.x;  row[5]=r1_.y;  row[6]=r1_.z;  row[7]=r1_.w; \
    row[8]=r2_.x;  row[9]=r2_.y;  row[10]=r2_.z; row[11]=r2_.w; \
    row[12]=r3_.x; row[13]=r3_.y; row[14]=r3_.z; row[15]=r3_.w; } while (0)

// ---------------------------------------------------------------------------
// Fused chain kernel (R13 math, R14 data path): 17 blocks x 64 threads.
// Math identical to verified R13: QR(M),QR(N) register MGS; A/W/CA/CB; base
// info-map E/F/H; interleaved LSB-first double-and-apply; epilogue P/K/Mc/Nb.
// R14 change: the 16x16 matmuls in the double/apply steps now run through
// stride-20 padded LDS with ds_read_b128 (batched issue, one wait) instead of
// per-element shuffles. gj16 / QR / assembly / epilogue are verified codepaths
// kept unchanged. Also: skip doubling steps whose bits can never be applied.
// ---------------------------------------------------------------------------
__global__ __launch_bounds__(64) void chain_k(
    const float* __restrict__ Mm, const float* __restrict__ Nm,
    const float* __restrict__ dvec, const float* __restrict__ Bm,
    const float* __restrict__ Cm, const float* __restrict__ nx,
    const float* __restrict__ na, const float* __restrict__ cov0,
    float* __restrict__ wsK, float* __restrict__ wsM, float* __restrict__ wsN)
{
    __shared__ float qm[16][17], qn[16][17], T0s[16][17];
    __shared__ float sC[32][17], sW[16][33], sAm[16][17], sBm[16][9];
    __shared__ float sCA[32][17], sCB[32][9], sP[16][17], sK[16][33];
    __shared__ float spv[16], d2[16], sNai[32], sNxi[16];
    // stride-20 matmul arenas: rows are 80B apart -> float4-aligned, and
    // column accesses hit <=2-way bank aliasing (free).
    __shared__ __attribute__((aligned(16))) float mE[16][20];
    __shared__ __attribute__((aligned(16))) float mET[16][20];
    __shared__ __attribute__((aligned(16))) float mF[16][20];
    __shared__ __attribute__((aligned(16))) float mH[16][20];
    __shared__ __attribute__((aligned(16))) float mZ[16][20];
    __shared__ __attribute__((aligned(16))) float mT[16][20];
    __shared__ __attribute__((aligned(16))) float mT2[16][20];
    __shared__ __attribute__((aligned(16))) float mL[16][20];
    const int lane = threadIdx.x;
    const int t = blockIdx.x;            // 0..16
    const int n = t + 1;                 // steps to apply
    const int i = lane & 15, gq = lane >> 4;
    const int jj = gq << 2;              // 4-wide column chunk this lane owns

    // ---- load inputs ----
    for (int e = lane; e < 256; e += 64) { qm[e >> 4][e & 15] = Mm[e]; qn[e >> 4][e & 15] = Nm[e]; }
    for (int e = lane; e < 512; e += 64) sC[e >> 4][e & 15] = Cm[e];
    for (int e = lane; e < 128; e += 64) sBm[e >> 3][e & 7] = Bm[e];
    if (lane < 16) {
        float s = softplus(dvec[lane]);
        spv[lane] = sqrtf(s);
        d2[lane] = 1.0f / sqrtf(1.0f + s);
        sNxi[lane] = 1.0f / (softplus(nx[lane]) + 1e-4f);
    }
    if (lane < 32) sNai[lane] = 1.0f / (softplus(na[lane]) + 1e-4f);
    __syncthreads();

    // ---- register MGS QR on both matrices (verified R12, rolled) ----
    {
        const int j0 = lane & 15;
        const int mi = lane >> 4;
        float (*Qs)[17] = (mi == 1) ? qn : qm;
        float col[16];
#pragma unroll
        for (int r = 0; r < 16; ++r) col[r] = Qs[r][j0];
        const int base = lane & 48;
#pragma unroll 1
        for (int j = 0; j < 16; ++j) {
            float qj[16];
#pragma unroll
            for (int r = 0; r < 16; ++r) qj[r] = __shfl(col[r], base + j);
            float nrm = 0.f;
#pragma unroll
            for (int r = 0; r < 16; ++r) nrm += qj[r] * qj[r];
            const float scal = 1.0f / sqrtf(nrm);
#pragma unroll
            for (int r = 0; r < 16; ++r) qj[r] *= scal;
            if (j0 == j) {
#pragma unroll
                for (int r = 0; r < 16; ++r) col[r] = qj[r];
            } else if (j0 > j) {
                float pr = 0.f;
#pragma unroll
                for (int r = 0; r < 16; ++r) pr += qj[r] * col[r];
#pragma unroll
                for (int r = 0; r < 16; ++r) col[r] -= pr * qj[r];
            }
        }
        __syncthreads();
        if (mi < 2) {
#pragma unroll
            for (int r = 0; r < 16; ++r) Qs[r][j0] = col[r];
        }
    }
    __syncthreads();

    // ---- assembly: A, W, base map E/F/H, CA, CB (verified patterns) ----
    for (int e = lane; e < 256; e += 64) {
        int ii = e >> 4, j = e & 15;
        float s = 0.f;
        for (int q = 0; q < 16; ++q) s += qm[ii][q] * d2[q] * qn[j][q];
        T0s[ii][j] = spv[ii] * s;
    }
    __syncthreads();
    for (int e = lane; e < 256; e += 64) {
        int ii = e >> 4, j = e & 15;
        float s = 0.f;
        for (int q = 0; q < 16; ++q) s += qn[ii][q] * T0s[q][j];
        sAm[ii][j] = s;
    }
    for (int e = lane; e < 512; e += 64) {
        int q = e >> 5, r = e & 31;
        sW[q][r] = sC[r][q] * sNai[r];
    }
    __syncthreads();
    for (int e = lane; e < 256; e += 64) {
        int ii = e >> 4, j = e & 15;
        float g = 0.f;
        for (int r = 0; r < 32; ++r) g += sC[r][ii] * sW[j][r];
        mF[ii][j] = g + ((ii == j) ? sNxi[ii] : 0.f);
        const float ev = sNxi[ii] * sAm[ii][j];
        mE[ii][j] = ev;
        mET[j][ii] = ev;
        float hsum = 0.f;
        for (int q = 0; q < 16; ++q) hsum += sAm[q][ii] * sNxi[q] * sAm[q][j];
        mH[ii][j] = hsum;
    }
    for (int e = lane; e < 512; e += 64) {
        int r = e >> 4, j = e & 15;
        float s = 0.f;
        for (int q = 0; q < 16; ++q) s += sC[r][q] * sAm[q][j];
        sCA[r][j] = s;
    }
    for (int e = lane; e < 256; e += 64) {
        int r = e >> 3, j = e & 7;
        float s = 0.f;
        for (int q = 0; q < 16; ++q) s += sC[r][q] * sBm[q][j];
        sCB[r][j] = s;
    }
    __syncthreads();

    // ---- L0 = inv(cov0) -> mL ----
    float aug[8];
#pragma unroll
    for (int k = 0; k < 8; ++k)
        aug[k] = (gq < 2) ? cov0[i * 16 + 8 * gq + k]
                          : ((8 * (gq - 2) + k == i) ? 1.f : 0.f);
    gj16(aug, i, gq);
    if (gq >= 2) {
        *(float4*)&mL[i][8 * (gq - 2)]     = make_float4(aug[0], aug[1], aug[2], aug[3]);
        *(float4*)&mL[i][8 * (gq - 2) + 4] = make_float4(aug[4], aug[5], aug[6], aug[7]);
    }
    __syncthreads();

    // ---- interleaved LSB-first double-and-apply (LDS-vectorized matmuls) ----
#pragma unroll 1
    for (int m = 0; m < 5; ++m) {
        if ((n >> m) & 1) {
            // apply: L = F - E (L+H)^-1 E^T
            if (gq < 2) {
                const float4 l0 = *(const float4*)&mL[i][8 * gq];
                const float4 l1 = *(const float4*)&mL[i][8 * gq + 4];
                const float4 h0 = *(const float4*)&mH[i][8 * gq];
                const float4 h1 = *(const float4*)&mH[i][8 * gq + 4];
                aug[0] = l0.x + h0.x; aug[1] = l0.y + h0.y;
                aug[2] = l0.z + h0.z; aug[3] = l0.w + h0.w;
                aug[4] = l1.x + h1.x; aug[5] = l1.y + h1.y;
                aug[6] = l1.z + h1.z; aug[7] = l1.w + h1.w;
            } else {
#pragma unroll
                for (int k = 0; k < 8; ++k) aug[k] = (8 * (gq - 2) + k == i) ? 1.f : 0.f;
            }
            gj16(aug, i, gq);
            if (gq >= 2) {
                *(float4*)&mZ[i][8 * (gq - 2)]     = make_float4(aug[0], aug[1], aug[2], aug[3]);
                *(float4*)&mZ[i][8 * (gq - 2) + 4] = make_float4(aug[4], aug[5], aug[6], aug[7]);
            }
            __syncthreads();
            // T = E * Z
            {
                float Er[16];
                LD_ROW16(mE, i, Er);
                float4 tacc = make_float4(0.f, 0.f, 0.f, 0.f);
#pragma unroll
                for (int q = 0; q < 16; ++q) {
                    const float4 zq = *(const float4*)&mZ[q][jj];
                    tacc.x += Er[q] * zq.x; tacc.y += Er[q] * zq.y;
                    tacc.z += Er[q] * zq.z; tacc.w += Er[q] * zq.w;
                }
                *(float4*)&mT[i][jj] = tacc;
            }
            __syncthreads();
            // L' = F - T * E^T
            {
                float Tr[16];
                LD_ROW16(mT, i, Tr);
                float4 l = *(const float4*)&mF[i][jj];
#pragma unroll
                for (int q = 0; q < 16; ++q) {
                    const float4 etq = *(const float4*)&mET[q][jj];
                    l.x -= Tr[q] * etq.x; l.y -= Tr[q] * etq.y;
                    l.z -= Tr[q] * etq.z; l.w -= Tr[q] * etq.w;
                }
                __syncthreads();
                *(float4*)&mL[i][jj] = l;
            }
            __syncthreads();
        }
        if (m < 4 && (n >> (m + 1)) != 0) {
            // double: Z=(F+H)^-1, T=EZ, T2=E^T Z, F'=F-T E^T, H'=H-T2 E, E'=T E
            if (gq < 2) {
                const float4 f0 = *(const float4*)&mF[i][8 * gq];
                const float4 f1 = *(const float4*)&mF[i][8 * gq + 4];
                const float4 h0 = *(const float4*)&mH[i][8 * gq];
                const float4 h1 = *(const float4*)&mH[i][8 * gq + 4];
                aug[0] = f0.x + h0.x; aug[1] = f0.y + h0.y;
                aug[2] = f0.z + h0.z; aug[3] = f0.w + h0.w;
                aug[4] = f1.x + h1.x; aug[5] = f1.y + h1.y;
                aug[6] = f1.z + h1.z; aug[7] = f1.w + h1.w;
            } else {
#pragma unroll
                for (int k = 0; k < 8; ++k) aug[k] = (8 * (gq - 2) + k == i) ? 1.f : 0.f;
            }
            gj16(aug, i, gq);
            if (gq >= 2) {
                *(float4*)&mZ[i][8 * (gq - 2)]     = make_float4(aug[0], aug[1], aug[2], aug[3]);
                *(float4*)&mZ[i][8 * (gq - 2) + 4] = make_float4(aug[4], aug[5], aug[6], aug[7]);
            }
            __syncthreads();
            // T = E*Z, T2 = E^T*Z (share Z reads)
            {
                float Er[16], ETr[16];
                LD_ROW16(mE, i, Er);
                LD_ROW16(mET, i, ETr);
                float4 tacc = make_float4(0.f, 0.f, 0.f, 0.f);
                float4 t2acc = make_float4(0.f, 0.f, 0.f, 0.f);
#pragma unroll
                for (int q = 0; q < 16; ++q) {
                    const float4 zq = *(const float4*)&mZ[q][jj];
                    tacc.x  += Er[q]  * zq.x; tacc.y  += Er[q]  * zq.y;
                    tacc.z  += Er[q]  * zq.z; tacc.w  += Er[q]  * zq.w;
                    t2acc.x += ETr[q] * zq.x; t2acc.y += ETr[q] * zq.y;
                    t2acc.z += ETr[q] * zq.z; t2acc.w += ETr[q] * zq.w;
                }
                *(float4*)&mT[i][jj]  = tacc;
                *(float4*)&mT2[i][jj] = t2acc;
            }
            __syncthreads();
            // F' = F - T*E^T ; H' = H - T2*E ; E' = T*E
            {
                float Tr[16], T2r[16];
                LD_ROW16(mT, i, Tr);
                LD_ROW16(mT2, i, T2r);
                float4 f  = *(const float4*)&mF[i][jj];
                float4 hh = *(const float4*)&mH[i][jj];
                float4 en = make_float4(0.f, 0.f, 0.f, 0.f);
#pragma unroll
                for (int q = 0; q < 16; ++q) {
                    const float4 eq  = *(const float4*)&mE[q][jj];
                    const float4 etq = *(const float4*)&mET[q][jj];
                    f.x  -= Tr[q]  * etq.x; f.y  -= Tr[q]  * etq.y;
                    f.z  -= Tr[q]  * etq.z; f.w  -= Tr[q]  * etq.w;
                    hh.x -= T2r[q] * eq.x;  hh.y -= T2r[q] * eq.y;
                    hh.z -= T2r[q] * eq.z;  hh.w -= T2r[q] * eq.w;
                    en.x += Tr[q]  * eq.x;  en.y += Tr[q]  * eq.y;
                    en.z += Tr[q]  * eq.z;  en.w += Tr[q]  * eq.w;
                }
                __syncthreads();   // all reads of E/ET/F/H done before overwrite
                *(float4*)&mF[i][jj] = f;
                *(float4*)&mH[i][jj] = hh;
                *(float4*)&mE[i][jj] = en;
                mET[jj + 0][i] = en.x; mET[jj + 1][i] = en.y;
                mET[jj + 2][i] = en.z; mET[jj + 3][i] = en.w;
            }
            __syncthreads();
        }
    }

    // ---- epilogue (verified math): P = L^-1, K = P W, Mc = A - K CA, Nb = B - K CB
    if (gq < 2) {
        const float4 l0 = *(const float4*)&mL[i][8 * gq];
        const float4 l1 = *(const float4*)&mL[i][8 * gq + 4];
        aug[0] = l0.x; aug[1] = l0.y; aug[2] = l0.z; aug[3] = l0.w;
        aug[4] = l1.x; aug[5] = l1.y; aug[6] = l1.z; aug[7] = l1.w;
    } else {
#pragma unroll
        for (int k = 0; k < 8; ++k) aug[k] = (8 * (gq - 2) + k == i) ? 1.f : 0.f;
    }
    gj16(aug, i, gq);
    if (gq >= 2) {
#pragma unroll
        for (int k = 0; k < 8; ++k) sP[i][8 * (gq - 2) + k] = aug[k];
    }
    __syncthreads();
#pragma unroll
    for (int m = 0; m < 8; ++m) {
        const int e = lane + 64 * m, ii = e >> 5, rr = e & 31;
        float s = 0.f;
#pragma unroll
        for (int q = 0; q < 16; ++q) s += sP[ii][q] * sW[q][rr];
        sK[ii][rr] = s;
        wsK[(size_t)t * 512 + e] = s;
    }
    __syncthreads();
#pragma unroll
    for (int m = 0; m < 4; ++m) {
        const int e = lane + 64 * m, ii = e >> 4, jjm = e & 15;
        float s = sAm[ii][jjm];
#pragma unroll
        for (int r = 0; r < 32; ++r) s -= sK[ii][r] * sCA[r][jjm];
        wsM[(size_t)t * 256 + e] = s;
    }
#pragma unroll
    for (int m = 0; m < 2; ++m) {
        const int e = lane + 64 * m, ii = e >> 3, jjm = e & 7;
        float s = sBm[ii][jjm];
#pragma unroll
        for (int r = 0; r < 32; ++r) s -= sK[ii][r] * sCB[r][jjm];
        wsN[(size_t)t * 128 + e] = s;
    }
}

// ---------------------------------------------------------------------------
// Phase A (verified R10-R12, unchanged).
// ---------------------------------------------------------------------------
__global__ __launch_bounds__(64) void phA_k(
    const float* __restrict__ u, const float* __restrict__ a,
    const float* __restrict__ wsK, const float* __restrict__ wsM,
    const float* __restrict__ wsN, float* __restrict__ wseg,
    float* __restrict__ wsp)
{
    const int lane = threadIdx.x;
    const int i = lane & 15, g = lane >> 4;
    const int seg = blockIdx.x >> 8;
    const int b = blockIdx.x & 255;

    float mcs[16][4];
#pragma unroll
    for (int j = 0; j < 16; ++j) {
        const int tc = (seg == 0) ? j : 16;
        const float4 v = *(const float4*)(wsM + (size_t)tc * 256 + i * 16 + 4 * g);
        mcs[j][0] = v.x; mcs[j][1] = v.y; mcs[j][2] = v.z; mcs[j][3] = v.w;
    }
    float kc[8], nbc[8];
    if (seg != 0) {
        const float4 k0 = *(const float4*)(wsK + (size_t)16 * 512 + i * 32 + 8 * g);
        const float4 k1 = *(const float4*)(wsK + (size_t)16 * 512 + i * 32 + 8 * g + 4);
        const float4 n0 = *(const float4*)(wsN + (size_t)16 * 128 + i * 8);
        const float4 n1 = *(const float4*)(wsN + (size_t)16 * 128 + i * 8 + 4);
        kc[0]=k0.x; kc[1]=k0.y; kc[2]=k0.z; kc[3]=k0.w;
        kc[4]=k1.x; kc[5]=k1.y; kc[6]=k1.z; kc[7]=k1.w;
        nbc[0]=n0.x; nbc[1]=n0.y; nbc[2]=n0.z; nbc[3]=n0.w;
        nbc[4]=n1.x; nbc[5]=n1.y; nbc[6]=n1.z; nbc[7]=n1.w;
    }

    float w = 0.f;
#pragma unroll
    for (int j = 0; j < 16; ++j) {
        const int t = 16 * seg + j;
        float kr[8], nbr[8];
        if (seg == 0) {
            const float4 k0 = *(const float4*)(wsK + (size_t)j * 512 + i * 32 + 8 * g);
            const float4 k1 = *(const float4*)(wsK + (size_t)j * 512 + i * 32 + 8 * g + 4);
            const float4 n0 = *(const float4*)(wsN + (size_t)j * 128 + i * 8);
            const float4 n1 = *(const float4*)(wsN + (size_t)j * 128 + i * 8 + 4);
            kr[0]=k0.x; kr[1]=k0.y; kr[2]=k0.z; kr[3]=k0.w;
            kr[4]=k1.x; kr[5]=k1.y; kr[6]=k1.z; kr[7]=k1.w;
            nbr[0]=n0.x; nbr[1]=n0.y; nbr[2]=n0.z; nbr[3]=n0.w;
            nbr[4]=n1.x; nbr[5]=n1.y; nbr[6]=n1.z; nbr[7]=n1.w;
        } else {
#pragma unroll
            for (int k = 0; k < 8; ++k) { kr[k] = kc[k]; nbr[k] = nbc[k]; }
        }
        const float a0 = a[(size_t)b * (TT * 32) + t * 32 + (lane & 31)];
        const float u0 = u[(size_t)b * (TT * 8) + t * 8 + (lane & 7)];
        float gvp = kr[0] * __shfl(a0, 8*g+0) + kr[1] * __shfl(a0, 8*g+1)
                  + kr[2] * __shfl(a0, 8*g+2) + kr[3] * __shfl(a0, 8*g+3)
                  + kr[4] * __shfl(a0, 8*g+4) + kr[5] * __shfl(a0, 8*g+5)
                  + kr[6] * __shfl(a0, 8*g+6) + kr[7] * __shfl(a0, 8*g+7);
        float nbs = nbr[0] * __shfl(u0,0) + nbr[1] * __shfl(u0,1)
                  + nbr[2] * __shfl(u0,2) + nbr[3] * __shfl(u0,3)
                  + nbr[4] * __shfl(u0,4) + nbr[5] * __shfl(u0,5)
                  + nbr[6] * __shfl(u0,6) + nbr[7] * __shfl(u0,7);
        gvp += (g == 3) ? nbs : 0.f;
        gvp += __shfl_xor(gvp, 16);
        gvp += __shfl_xor(gvp, 32);
        float part = mcs[j][0] * __shfl(w, 4*g+0) + mcs[j][1] * __shfl(w, 4*g+1)
                   + mcs[j][2] * __shfl(w, 4*g+2) + mcs[j][3] * __shfl(w, 4*g+3);
        part += __shfl_xor(part, 16);
        part += __shfl_xor(part, 32);
        w = part + gvp;
    }
    if (lane < 16) wseg[(size_t)seg * 4096 + b * 16 + i] = w;

    if (blockIdx.x == 0) {          // P0 = Mc15 ... Mc0
        float pr[4];
#pragma unroll
        for (int k = 0; k < 4; ++k) pr[k] = (4 * g + k == i) ? 1.f : 0.f;
#pragma unroll
        for (int j = 0; j < 16; ++j) {
            float np[4] = {0.f, 0.f, 0.f, 0.f};
#pragma unroll
            for (int q = 0; q < 16; ++q) {
                const float mq = __shfl(mcs[j][q & 3], i + 16 * (q >> 2));
#pragma unroll
                for (int k = 0; k < 4; ++k) np[k] += mq * __shfl(pr[k], q + 16 * g);
            }
#pragma unroll
            for (int k = 0; k < 4; ++k) pr[k] = np[k];
        }
#pragma unroll
        for (int k = 0; k < 4; ++k) wsp[i * 16 + 4 * g + k] = pr[k];
    }
    if (blockIdx.x == 256) {        // PP = Mc16^16
        float pr[4];
#pragma unroll
        for (int k = 0; k < 4; ++k) pr[k] = mcs[0][k];
#pragma unroll
        for (int r = 0; r < 4; ++r) {
            float np[4] = {0.f, 0.f, 0.f, 0.f};
#pragma unroll
            for (int q = 0; q < 16; ++q) {
                const float sq = __shfl(pr[q & 3], i + 16 * (q >> 2));
#pragma unroll
                for (int k = 0; k < 4; ++k) np[k] += sq * __shfl(pr[k], q + 16 * g);
            }
#pragma unroll
            for (int k = 0; k < 4; ++k) pr[k] = np[k];
        }
#pragma unroll
        for (int k = 0; k < 4; ++k) wsp[256 + i * 16 + 4 * g + k] = pr[k];
    }
}

// ---------------------------------------------------------------------------
// Phase B (verified R9-R12, unchanged).
// ---------------------------------------------------------------------------
__global__ __launch_bounds__(64) void phB_k(
    const float* __restrict__ mean0, const float* __restrict__ wsp,
    const float* __restrict__ wseg, float* __restrict__ bnd)
{
    const int lane = threadIdx.x;
    const int i = lane & 15, g = lane >> 4;
    const int b = blockIdx.x;

    const float4 v0 = *(const float4*)(wsp + i * 16 + 4 * g);
    const float4 vp = *(const float4*)(wsp + 256 + i * 16 + 4 * g);
    const float m0s[4] = {v0.x, v0.y, v0.z, v0.w};
    const float mps[4] = {vp.x, vp.y, vp.z, vp.w};
    float wv[16];
#pragma unroll
    for (int s = 0; s < 16; ++s) wv[s] = wseg[(size_t)s * 4096 + b * 16 + i];

    float mn = mean0[b * 16 + i];
#pragma unroll
    for (int s = 0; s < 16; ++s) {
        if (lane < 16) bnd[(size_t)s * 4096 + b * 16 + i] = mn;
        const float c0 = (s == 0) ? m0s[0] : mps[0];
        const float c1 = (s == 0) ? m0s[1] : mps[1];
        const float c2 = (s == 0) ? m0s[2] : mps[2];
        const float c3 = (s == 0) ? m0s[3] : mps[3];
        float part = c0 * __shfl(mn, 4 * g + 0) + c1 * __shfl(mn, 4 * g + 1)
                   + c2 * __shfl(mn, 4 * g + 2) + c3 * __shfl(mn, 4 * g + 3);
        part += __shfl_xor(part, 16);
        part += __shfl_xor(part, 32);
        mn = part + wv[s];
    }
}

// ---------------------------------------------------------------------------
// Phase C (verified R10-R12, unchanged).
// ---------------------------------------------------------------------------
__global__ __launch_bounds__(64) void phC_k(
    const float* __restrict__ u, const float* __restrict__ a,
    const float* __restrict__ wsK, const float* __restrict__ wsM,
    const float* __restrict__ wsN, const float* __restrict__ bnd,
    float* __restrict__ out)
{
    const int lane = threadIdx.x;
    const int i = lane & 15, g = lane >> 4;
    const int seg = blockIdx.x >> 8;
    const int b = blockIdx.x & 255;

    float mcs[16][4];
#pragma unroll
    for (int j = 0; j < 16; ++j) {
        const int tc = (seg == 0) ? j : 16;
        const float4 v = *(const float4*)(wsM + (size_t)tc * 256 + i * 16 + 4 * g);
        mcs[j][0] = v.x; mcs[j][1] = v.y; mcs[j][2] = v.z; mcs[j][3] = v.w;
    }
    float kc[8], nbc[8];
    if (seg != 0) {
        const float4 k0 = *(const float4*)(wsK + (size_t)16 * 512 + i * 32 + 8 * g);
        const float4 k1 = *(const float4*)(wsK + (size_t)16 * 512 + i * 32 + 8 * g + 4);
        const float4 n0 = *(const float4*)(wsN + (size_t)16 * 128 + i * 8);
        const float4 n1 = *(const float4*)(wsN + (size_t)16 * 128 + i * 8 + 4);
        kc[0]=k0.x; kc[1]=k0.y; kc[2]=k0.z; kc[3]=k0.w;
        kc[4]=k1.x; kc[5]=k1.y; kc[6]=k1.z; kc[7]=k1.w;
        nbc[0]=n0.x; nbc[1]=n0.y; nbc[2]=n0.z; nbc[3]=n0.w;
        nbc[4]=n1.x; nbc[5]=n1.y; nbc[6]=n1.z; nbc[7]=n1.w;
    }

    float mn = bnd[(size_t)seg * 4096 + b * 16 + i];
    float* ob = out + (size_t)b * 4096 + (size_t)(16 * seg) * 16;
#pragma unroll
    for (int j = 0; j < 16; ++j) {
        const int t = 16 * seg + j;
        float kr[8], nbr[8];
        if (seg == 0) {
            const float4 k0 = *(const float4*)(wsK + (size_t)j * 512 + i * 32 + 8 * g);
            const float4 k1 = *(const float4*)(wsK + (size_t)j * 512 + i * 32 + 8 * g + 4);
            const float4 n0 = *(const float4*)(wsN + (size_t)j * 128 + i * 8);
            const float4 n1 = *(const float4*)(wsN + (size_t)j * 128 + i * 8 + 4);
            kr[0]=k0.x; kr[1]=k0.y; kr[2]=k0.z; kr[3]=k0.w;
            kr[4]=k1.x; kr[5]=k1.y; kr[6]=k1.z; kr[7]=k1.w;
            nbr[0]=n0.x; nbr[1]=n0.y; nbr[2]=n0.z; nbr[3]=n0.w;
            nbr[4]=n1.x; nbr[5]=n1.y; nbr[6]=n1.z; nbr[7]=n1.w;
        } else {
#pragma unroll
            for (int k = 0; k < 8; ++k) { kr[k] = kc[k]; nbr[k] = nbc[k]; }
        }
        const float a0 = a[(size_t)b * (TT * 32) + t * 32 + (lane & 31)];
        const float u0 = u[(size_t)b * (TT * 8) + t * 8 + (lane & 7)];
        float gvp = kr[0] * __shfl(a0, 8*g+0) + kr[1] * __shfl(a0, 8*g+1)
                  + kr[2] * __shfl(a0, 8*g+2) + kr[3] * __shfl(a0, 8*g+3)
                  + kr[4] * __shfl(a0, 8*g+4) + kr[5] * __shfl(a0, 8*g+5)
                  + kr[6] * __shfl(a0, 8*g+6) + kr[7] * __shfl(a0, 8*g+7);
        float nbs = nbr[0] * __shfl(u0,0) + nbr[1] * __shfl(u0,1)
                  + nbr[2] * __shfl(u0,2) + nbr[3] * __shfl(u0,3)
                  + nbr[4] * __shfl(u0,4) + nbr[5] * __shfl(u0,5)
                  + nbr[6] * __shfl(u0,6) + nbr[7] * __shfl(u0,7);
        gvp += (g == 3) ? nbs : 0.f;
        gvp += __shfl_xor(gvp, 16);
        gvp += __shfl_xor(gvp, 32);
        float part = mcs[j][0] * __shfl(mn, 4*g+0) + mcs[j][1] * __shfl(mn, 4*g+1)
                   + mcs[j][2] * __shfl(mn, 4*g+2) + mcs[j][3] * __shfl(mn, 4*g+3);
        part += __shfl_xor(part, 16);
        part += __shfl_xor(part, 32);
        mn = part + gvp;
        if (lane < 16) ob[j * 16 + i] = mn;
    }
}

// ---------------------------------------------------------------------------
// Fallback (verified R6/R8/R9, unchanged): serial mean pass if ws too small.
// ---------------------------------------------------------------------------
__global__ __launch_bounds__(64) void meanf_k(
    const float* __restrict__ mean0, const float* __restrict__ u,
    const float* __restrict__ a, const float* __restrict__ wsK,
    const float* __restrict__ wsM, const float* __restrict__ wsN,
    float* __restrict__ out)
{
    const int lane = threadIdx.x;
    const int b = blockIdx.x;
    const int i = lane & 15;
    const int g = lane >> 4;

    const float* ub = u + (size_t)b * TT * 8;
    const float* ab = a + (size_t)b * TT * 32;
    float* ob = out + (size_t)b * TT * 16;

    float mn = mean0[b * 16 + i];
    float Mc[16];
    {
        const float4* p = (const float4*)(wsM + i * 16);
        float4 x0 = p[0], x1 = p[1], x2 = p[2], x3 = p[3];
        Mc[0]=x0.x; Mc[1]=x0.y; Mc[2]=x0.z; Mc[3]=x0.w;
        Mc[4]=x1.x; Mc[5]=x1.y; Mc[6]=x1.z; Mc[7]=x1.w;
        Mc[8]=x2.x; Mc[9]=x2.y; Mc[10]=x2.z; Mc[11]=x2.w;
        Mc[12]=x3.x; Mc[13]=x3.y; Mc[14]=x3.z; Mc[15]=x3.w;
    }
    float gv;
    {
        float4 k0 = *(const float4*)(wsK + i * 32 + 8 * g);
        float4 k1 = *(const float4*)(wsK + i * 32 + 8 * g + 4);
        float4 n0 = *(const float4*)(wsN + i * 8);
        float4 n1 = *(const float4*)(wsN + i * 8 + 4);
        float u0 = ub[lane & 7];
        float a0 = ab[lane & 31];
        float part = k0.x * __shfl(a0, 8*g+0) + k0.y * __shfl(a0, 8*g+1)
                   + k0.z * __shfl(a0, 8*g+2) + k0.w * __shfl(a0, 8*g+3)
                   + k1.x * __shfl(a0, 8*g+4) + k1.y * __shfl(a0, 8*g+5)
                   + k1.z * __shfl(a0, 8*g+6) + k1.w * __shfl(a0, 8*g+7);
        float nbs = n0.x * __shfl(u0,0) + n0.y * __shfl(u0,1)
                  + n0.z * __shfl(u0,2) + n0.w * __shfl(u0,3)
                  + n1.x * __shfl(u0,4) + n1.y * __shfl(u0,5)
                  + n1.z * __shfl(u0,6) + n1.w * __shfl(u0,7);
        part += (g == 3) ? nbs : 0.f;
        part += __shfl_xor(part, 16);
        part += __shfl_xor(part, 32);
        gv = part;
    }
    float4 mA, mB, mC, mD, kp0, kp1, np0, np1;
    float upn, apn;
    {
        const float4* p = (const float4*)(wsM + 256 + i * 16);
        mA = p[0]; mB = p[1]; mC = p[2]; mD = p[3];
        kp0 = *(const float4*)(wsK + 512 + i * 32 + 8 * g);
        kp1 = *(const float4*)(wsK + 512 + i * 32 + 8 * g + 4);
        np0 = *(const float4*)(wsN + 128 + i * 8);
        np1 = *(const float4*)(wsN + 128 + i * 8 + 4);
        upn = ub[8 + (lane & 7)];
        apn = ab[32 + (lane & 31)];
    }

    for (int t = 0; t < TT; ++t) {
        const int t2 = (t + 2 < TT) ? t + 2 : TT - 1;
        const int s2 = (t2 < WARM) ? t2 : WARM;
        const float4* mp = (const float4*)(wsM + (size_t)s2 * 256 + i * 16);
        float4 l0 = mp[0], l1 = mp[1], l2 = mp[2], l3 = mp[3];
        float4 kl0 = *(const float4*)(wsK + (size_t)s2 * 512 + i * 32 + 8 * g);
        float4 kl1 = *(const float4*)(wsK + (size_t)s2 * 512 + i * 32 + 8 * g + 4);
        float4 nl0 = *(const float4*)(wsN + (size_t)s2 * 128 + i * 8);
        float4 nl1 = *(const float4*)(wsN + (size_t)s2 * 128 + i * 8 + 4);
        float ul = ub[t2 * 8 + (lane & 7)];
        float al = ab[t2 * 32 + (lane & 31)];

        float s0 = gv, s1 = 0.f, s2f = 0.f, s3 = 0.f;
#pragma unroll
        for (int q = 0; q < 16; q += 4) {
            s0  += Mc[q]     * __shfl(mn, q);
            s1  += Mc[q + 1] * __shfl(mn, q + 1);
            s2f += Mc[q + 2] * __shfl(mn, q + 2);
            s3  += Mc[q + 3] * __shfl(mn, q + 3);
        }
        mn = (s0 + s1) + (s2f + s3);
        if (lane < 16) ob[t * 16 + lane] = mn;

        float part = kp0.x * __shfl(apn, 8*g+0) + kp0.y * __shfl(apn, 8*g+1)
                   + kp0.z * __shfl(apn, 8*g+2) + kp0.w * __shfl(apn, 8*g+3)
                   + kp1.x * __shfl(apn, 8*g+4) + kp1.y * __shfl(apn, 8*g+5)
                   + kp1.z * __shfl(apn, 8*g+6) + kp1.w * __shfl(apn, 8*g+7);
        float nbs = np0.x * __shfl(upn,0) + np0.y * __shfl(upn,1)
                  + np0.z * __shfl(upn,2) + np0.w * __shfl(upn,3)
                  + np1.x * __shfl(upn,4) + np1.y * __shfl(upn,5)
                  + np1.z * __shfl(upn,6) + np1.w * __shfl(upn,7);
        part += (g == 3) ? nbs : 0.f;
        part += __shfl_xor(part, 16);
        part += __shfl_xor(part, 32);
        gv = part;

        Mc[0]=mA.x; Mc[1]=mA.y; Mc[2]=mA.z; Mc[3]=mA.w;
        Mc[4]=mB.x; Mc[5]=mB.y; Mc[6]=mB.z; Mc[7]=mB.w;
        Mc[8]=mC.x; Mc[9]=mC.y; Mc[10]=mC.z; Mc[11]=mC.w;
        Mc[12]=mD.x; Mc[13]=mD.y; Mc[14]=mD.z; Mc[15]=mD.w;
        mA = l0; mB = l1; mC = l2; mD = l3;
        kp0 = kl0; kp1 = kl1; np0 = nl0; np1 = nl1;
        upn = ul; apn = al;
    }
}

extern "C" void kernel_launch(void* const* d_in, const int* in_sizes, int n_in,
                              void* d_out, int out_size, void* d_ws, size_t ws_size,
                              hipStream_t stream) {
    const float* mean0 = nullptr; const float* cov0 = nullptr;
    const float* u = nullptr;     const float* a = nullptr;
    const float* Mm = nullptr;    const float* Nm = nullptr;
    const float* dv = nullptr;    const float* Bm = nullptr;
    const float* Cm = nullptr;    const float* nxp = nullptr;
    const float* nap = nullptr;
    for (int i = 0; i < n_in; ++i) {
        const float* p = (const float*)d_in[i];
        switch (in_sizes[i]) {
            case 256 * 16:        mean0 = p; break;
            case 256 * 256:       cov0 = p; break;
            case 256 * 256 * 8:   u = p; break;
            case 256 * 256 * 32:  a = p; break;
            case 256:             if (!Mm) Mm = p; else Nm = p; break;
            case 16:              if (!dv) dv = p; else nxp = p; break;
            case 128:             Bm = p; break;
            case 512:             Cm = p; break;
            case 32:              nap = p; break;
            default: break;
        }
    }
    float* ws   = (float*)d_ws;
    float* wsK  = ws + OFF_K;
    float* wsM  = ws + OFF_MC;
    float* wsN  = ws + OFF_NB;
    float* wsp  = ws + OFF_P0;
    float* wseg = ws + OFF_WSEG;
    float* bnd  = ws + OFF_BND;

    chain_k<<<WARM + 1, 64, 0, stream>>>(Mm, Nm, dv, Bm, Cm, nxp, nap, cov0,
                                         wsK, wsM, wsN);
    if (ws_size >= NEED_WS_BYTES) {
        phA_k<<<16 * 256, 64, 0, stream>>>(u, a, wsK, wsM, wsN, wseg, wsp);
        phB_k<<<256, 64, 0, stream>>>(mean0, wsp, wseg, bnd);
        phC_k<<<16 * 256, 64, 0, stream>>>(u, a, wsK, wsM, wsN, bnd, (float*)d_out);
    } else {
        meanf_k<<<256, 64, 0, stream>>>(mean0, u, a, wsK, wsM, wsN, (float*)d_out);
    }
}

// Round 2
// 176.687 us; speedup vs baseline: 1.2393x; 1.2393x over previous
//
#include <hip/hip_runtime.h>
#include <math.h>

#define TT 256
#define WARM 16
// ws float offsets (chain outputs + scan intermediates only)
#define OFF_K    5632   // 17 x 512 -> 14336
#define OFF_MC   14336  // 17 x 256 -> 18688
#define OFF_NB   18688  // 17 x 128 -> 20864
#define OFF_P0   20864  // Mseg0 (256) -> 21120
#define OFF_PP   21120  // Mc16^16 (256) -> 21376
#define OFF_WSEG 21376  // 16 x 256 x 16 -> 86912
#define OFF_BND  86912  // 16 x 256 x 16 -> 152448
#define NEED_WS_BYTES ((size_t)152448 * 4)

__device__ __forceinline__ float softplus(float v) {
    return fmaxf(v, 0.0f) + log1pf(expf(-fabsf(v)));
}

// Shuffle-based Gauss-Jordan, [X|I] -> [I|X^-1] (verified R5-R12).
// Layout: lane (i, gq) holds aug[i][8*gq+k], k=0..7.
__device__ __forceinline__ void gj16(float (&aug)[8], const int i, const int gq) {
#pragma unroll
    for (int j = 0; j < 16; ++j) {
        float prow[8];
#pragma unroll
        for (int k = 0; k < 8; ++k) prow[k] = __shfl(aug[k], j + 16 * gq);
        const float pjj = __shfl(aug[j & 7], j + 16 * (j >> 3));
        const float cij = __shfl(aug[j & 7], i + 16 * (j >> 3));
        const float pivinv = 1.0f / pjj;
        const float f = cij * pivinv;
#pragma unroll
        for (int k = 0; k < 8; ++k)
            aug[k] = (i == j) ? prow[k] * pivinv : aug[k] - f * prow[k];
    }
}

// Load a full 16-float row from a stride-20 LDS matrix into registers (4x b128).
#define LD_ROW16(Mt, r, row) do { \
    const float4 r0_ = *(const float4*)&Mt[r][0]; \
    const float4 r1_ = *(const float4*)&Mt[r][4]; \
    const float4 r2_ = *(const float4*)&Mt[r][8]; \
    const float4 r3_ = *(const float4*)&Mt[r][12]; \
    row[0]=r0_.x;  row[1]=r0_.y;  row[2]=r0_.z;  row[3]=r0_.w; \
    row[4]=r1_.x;  row[5]=r1_.y;  row[6]=r1_.z;  row[7]=r1_.w; \
    row[8]=r2_.x;  row[9]=r2_.y;  row[10]=r2_.z; row[11]=r2_.w; \
    row[12]=r3_.x; row[13]=r3_.y; row[14]=r3_.z; row[15]=r3_.w; } while (0)

// ---------------------------------------------------------------------------
// Fused chain kernel (R13 math, R15 data path): 17 blocks x 64 threads.
// Math & barrier placement identical to verified R14. R15 change: every
// LDS-matmul issues ALL its column loads into an explicitly-unrolled register
// array FIRST (batched ds_read_b128, one lgkmcnt wait), then runs the FMA
// loop; E-row/ET-row operands stay register-resident across the m-loop
// (reloaded only after a double rewrites E). This is purely a load-scheduling
// change targeting R14's observed serialization (VGPR 88 -> loads not hoisted).
// ---------------------------------------------------------------------------
__global__ __launch_bounds__(64) void chain_k(
    const float* __restrict__ Mm, const float* __restrict__ Nm,
    const float* __restrict__ dvec, const float* __restrict__ Bm,
    const float* __restrict__ Cm, const float* __restrict__ nx,
    const float* __restrict__ na, const float* __restrict__ cov0,
    float* __restrict__ wsK, float* __restrict__ wsM, float* __restrict__ wsN)
{
    __shared__ float qm[16][17], qn[16][17], T0s[16][17];
    __shared__ float sC[32][17], sW[16][33], sAm[16][17], sBm[16][9];
    __shared__ float sCA[32][17], sCB[32][9], sP[16][17], sK[16][33];
    __shared__ float spv[16], d2[16], sNai[32], sNxi[16];
    // stride-20 matmul arenas: rows are 80B apart -> float4-aligned, and
    // column accesses hit <=2-way bank aliasing (free).
    __shared__ __attribute__((aligned(16))) float mE[16][20];
    __shared__ __attribute__((aligned(16))) float mET[16][20];
    __shared__ __attribute__((aligned(16))) float mF[16][20];
    __shared__ __attribute__((aligned(16))) float mH[16][20];
    __shared__ __attribute__((aligned(16))) float mZ[16][20];
    __shared__ __attribute__((aligned(16))) float mT[16][20];
    __shared__ __attribute__((aligned(16))) float mT2[16][20];
    __shared__ __attribute__((aligned(16))) float mL[16][20];
    const int lane = threadIdx.x;
    const int t = blockIdx.x;            // 0..16
    const int n = t + 1;                 // steps to apply
    const int i = lane & 15, gq = lane >> 4;
    const int jj = gq << 2;              // 4-wide column chunk this lane owns

    // ---- load inputs ----
    for (int e = lane; e < 256; e += 64) { qm[e >> 4][e & 15] = Mm[e]; qn[e >> 4][e & 15] = Nm[e]; }
    for (int e = lane; e < 512; e += 64) sC[e >> 4][e & 15] = Cm[e];
    for (int e = lane; e < 128; e += 64) sBm[e >> 3][e & 7] = Bm[e];
    if (lane < 16) {
        float s = softplus(dvec[lane]);
        spv[lane] = sqrtf(s);
        d2[lane] = 1.0f / sqrtf(1.0f + s);
        sNxi[lane] = 1.0f / (softplus(nx[lane]) + 1e-4f);
    }
    if (lane < 32) sNai[lane] = 1.0f / (softplus(na[lane]) + 1e-4f);
    __syncthreads();

    // ---- register MGS QR on both matrices (verified R12, rolled) ----
    {
        const int j0 = lane & 15;
        const int mi = lane >> 4;
        float (*Qs)[17] = (mi == 1) ? qn : qm;
        float col[16];
#pragma unroll
        for (int r = 0; r < 16; ++r) col[r] = Qs[r][j0];
        const int base = lane & 48;
#pragma unroll 1
        for (int j = 0; j < 16; ++j) {
            float qj[16];
#pragma unroll
            for (int r = 0; r < 16; ++r) qj[r] = __shfl(col[r], base + j);
            float nrm = 0.f;
#pragma unroll
            for (int r = 0; r < 16; ++r) nrm += qj[r] * qj[r];
            const float scal = 1.0f / sqrtf(nrm);
#pragma unroll
            for (int r = 0; r < 16; ++r) qj[r] *= scal;
            if (j0 == j) {
#pragma unroll
                for (int r = 0; r < 16; ++r) col[r] = qj[r];
            } else if (j0 > j) {
                float pr = 0.f;
#pragma unroll
                for (int r = 0; r < 16; ++r) pr += qj[r] * col[r];
#pragma unroll
                for (int r = 0; r < 16; ++r) col[r] -= pr * qj[r];
            }
        }
        __syncthreads();
        if (mi < 2) {
#pragma unroll
            for (int r = 0; r < 16; ++r) Qs[r][j0] = col[r];
        }
    }
    __syncthreads();

    // ---- assembly: A, W, base map E/F/H, CA, CB (verified patterns) ----
    for (int e = lane; e < 256; e += 64) {
        int ii = e >> 4, j = e & 15;
        float s = 0.f;
        for (int q = 0; q < 16; ++q) s += qm[ii][q] * d2[q] * qn[j][q];
        T0s[ii][j] = spv[ii] * s;
    }
    __syncthreads();
    for (int e = lane; e < 256; e += 64) {
        int ii = e >> 4, j = e & 15;
        float s = 0.f;
        for (int q = 0; q < 16; ++q) s += qn[ii][q] * T0s[q][j];
        sAm[ii][j] = s;
    }
    for (int e = lane; e < 512; e += 64) {
        int q = e >> 5, r = e & 31;
        sW[q][r] = sC[r][q] * sNai[r];
    }
    __syncthreads();
    for (int e = lane; e < 256; e += 64) {
        int ii = e >> 4, j = e & 15;
        float g = 0.f;
        for (int r = 0; r < 32; ++r) g += sC[r][ii] * sW[j][r];
        mF[ii][j] = g + ((ii == j) ? sNxi[ii] : 0.f);
        const float ev = sNxi[ii] * sAm[ii][j];
        mE[ii][j] = ev;
        mET[j][ii] = ev;
        float hsum = 0.f;
        for (int q = 0; q < 16; ++q) hsum += sAm[q][ii] * sNxi[q] * sAm[q][j];
        mH[ii][j] = hsum;
    }
    for (int e = lane; e < 512; e += 64) {
        int r = e >> 4, j = e & 15;
        float s = 0.f;
        for (int q = 0; q < 16; ++q) s += sC[r][q] * sAm[q][j];
        sCA[r][j] = s;
    }
    for (int e = lane; e < 256; e += 64) {
        int r = e >> 3, j = e & 7;
        float s = 0.f;
        for (int q = 0; q < 16; ++q) s += sC[r][q] * sBm[q][j];
        sCB[r][j] = s;
    }
    __syncthreads();

    // ---- E rows register-resident across the m-loop (R13-style residency) ----
    float Er[16], ETr[16];
    LD_ROW16(mE, i, Er);
    LD_ROW16(mET, i, ETr);

    // ---- L0 = inv(cov0) -> mL ----
    float aug[8];
#pragma unroll
    for (int k = 0; k < 8; ++k)
        aug[k] = (gq < 2) ? cov0[i * 16 + 8 * gq + k]
                          : ((8 * (gq - 2) + k == i) ? 1.f : 0.f);
    gj16(aug, i, gq);
    if (gq >= 2) {
        *(float4*)&mL[i][8 * (gq - 2)]     = make_float4(aug[0], aug[1], aug[2], aug[3]);
        *(float4*)&mL[i][8 * (gq - 2) + 4] = make_float4(aug[4], aug[5], aug[6], aug[7]);
    }
    __syncthreads();

    // ---- interleaved LSB-first double-and-apply (batched-LDS matmuls) ----
#pragma unroll 1
    for (int m = 0; m < 5; ++m) {
        if ((n >> m) & 1) {
            // apply: L = F - E (L+H)^-1 E^T
            if (gq < 2) {
                const float4 l0 = *(const float4*)&mL[i][8 * gq];
                const float4 l1 = *(const float4*)&mL[i][8 * gq + 4];
                const float4 h0 = *(const float4*)&mH[i][8 * gq];
                const float4 h1 = *(const float4*)&mH[i][8 * gq + 4];
                aug[0] = l0.x + h0.x; aug[1] = l0.y + h0.y;
                aug[2] = l0.z + h0.z; aug[3] = l0.w + h0.w;
                aug[4] = l1.x + h1.x; aug[5] = l1.y + h1.y;
                aug[6] = l1.z + h1.z; aug[7] = l1.w + h1.w;
            } else {
#pragma unroll
                for (int k = 0; k < 8; ++k) aug[k] = (8 * (gq - 2) + k == i) ? 1.f : 0.f;
            }
            gj16(aug, i, gq);
            if (gq >= 2) {
                *(float4*)&mZ[i][8 * (gq - 2)]     = make_float4(aug[0], aug[1], aug[2], aug[3]);
                *(float4*)&mZ[i][8 * (gq - 2) + 4] = make_float4(aug[4], aug[5], aug[6], aug[7]);
            }
            __syncthreads();
            // T = E * Z : batch ALL column loads first, then FMA
            {
                float4 zz[16];
#pragma unroll
                for (int q = 0; q < 16; ++q) zz[q] = *(const float4*)&mZ[q][jj];
                float4 tacc = make_float4(0.f, 0.f, 0.f, 0.f);
#pragma unroll
                for (int q = 0; q < 16; ++q) {
                    tacc.x += Er[q] * zz[q].x; tacc.y += Er[q] * zz[q].y;
                    tacc.z += Er[q] * zz[q].z; tacc.w += Er[q] * zz[q].w;
                }
                *(float4*)&mT[i][jj] = tacc;
            }
            __syncthreads();
            // L' = F - T * E^T : batch T-row + all ET columns, then FMA
            {
                float Tr[16];
                LD_ROW16(mT, i, Tr);
                float4 et[16];
#pragma unroll
                for (int q = 0; q < 16; ++q) et[q] = *(const float4*)&mET[q][jj];
                float4 l = *(const float4*)&mF[i][jj];
#pragma unroll
                for (int q = 0; q < 16; ++q) {
                    l.x -= Tr[q] * et[q].x; l.y -= Tr[q] * et[q].y;
                    l.z -= Tr[q] * et[q].z; l.w -= Tr[q] * et[q].w;
                }
                __syncthreads();
                *(float4*)&mL[i][jj] = l;
            }
            __syncthreads();
        }
        if (m < 4 && (n >> (m + 1)) != 0) {
            // double: Z=(F+H)^-1, T=EZ, T2=E^T Z, F'=F-T E^T, H'=H-T2 E, E'=T E
            if (gq < 2) {
                const float4 f0 = *(const float4*)&mF[i][8 * gq];
                const float4 f1 = *(const float4*)&mF[i][8 * gq + 4];
                const float4 h0 = *(const float4*)&mH[i][8 * gq];
                const float4 h1 = *(const float4*)&mH[i][8 * gq + 4];
                aug[0] = f0.x + h0.x; aug[1] = f0.y + h0.y;
                aug[2] = f0.z + h0.z; aug[3] = f0.w + h0.w;
                aug[4] = f1.x + h1.x; aug[5] = f1.y + h1.y;
                aug[6] = f1.z + h1.z; aug[7] = f1.w + h1.w;
            } else {
#pragma unroll
                for (int k = 0; k < 8; ++k) aug[k] = (8 * (gq - 2) + k == i) ? 1.f : 0.f;
            }
            gj16(aug, i, gq);
            if (gq >= 2) {
                *(float4*)&mZ[i][8 * (gq - 2)]     = make_float4(aug[0], aug[1], aug[2], aug[3]);
                *(float4*)&mZ[i][8 * (gq - 2) + 4] = make_float4(aug[4], aug[5], aug[6], aug[7]);
            }
            __syncthreads();
            // T = E*Z, T2 = E^T*Z : batch Z columns once, share
            {
                float4 zz[16];
#pragma unroll
                for (int q = 0; q < 16; ++q) zz[q] = *(const float4*)&mZ[q][jj];
                float4 tacc = make_float4(0.f, 0.f, 0.f, 0.f);
                float4 t2acc = make_float4(0.f, 0.f, 0.f, 0.f);
#pragma unroll
                for (int q = 0; q < 16; ++q) {
                    tacc.x  += Er[q]  * zz[q].x; tacc.y  += Er[q]  * zz[q].y;
                    tacc.z  += Er[q]  * zz[q].z; tacc.w  += Er[q]  * zz[q].w;
                    t2acc.x += ETr[q] * zz[q].x; t2acc.y += ETr[q] * zz[q].y;
                    t2acc.z += ETr[q] * zz[q].z; t2acc.w += ETr[q] * zz[q].w;
                }
                *(float4*)&mT[i][jj]  = tacc;
                *(float4*)&mT2[i][jj] = t2acc;
            }
            __syncthreads();
            // F' = F - T*E^T ; H' = H - T2*E ; E' = T*E   (E cols in halves of 8)
            {
                float Tr[16], T2r[16];
                LD_ROW16(mT, i, Tr);
                LD_ROW16(mT2, i, T2r);
                float4 f  = *(const float4*)&mF[i][jj];
                float4 hh = *(const float4*)&mH[i][jj];
                float4 en = make_float4(0.f, 0.f, 0.f, 0.f);
#pragma unroll
                for (int qh = 0; qh < 16; qh += 8) {
                    float4 eq[8], etq[8];
#pragma unroll
                    for (int q0 = 0; q0 < 8; ++q0) {
                        eq[q0]  = *(const float4*)&mE[qh + q0][jj];
                        etq[q0] = *(const float4*)&mET[qh + q0][jj];
                    }
#pragma unroll
                    for (int q0 = 0; q0 < 8; ++q0) {
                        const float tq = Tr[qh + q0], t2q = T2r[qh + q0];
                        f.x  -= tq  * etq[q0].x; f.y  -= tq  * etq[q0].y;
                        f.z  -= tq  * etq[q0].z; f.w  -= tq  * etq[q0].w;
                        hh.x -= t2q * eq[q0].x;  hh.y -= t2q * eq[q0].y;
                        hh.z -= t2q * eq[q0].z;  hh.w -= t2q * eq[q0].w;
                        en.x += tq  * eq[q0].x;  en.y += tq  * eq[q0].y;
                        en.z += tq  * eq[q0].z;  en.w += tq  * eq[q0].w;
                    }
                }
                __syncthreads();   // all reads of E/ET/F/H done before overwrite
                *(float4*)&mF[i][jj] = f;
                *(float4*)&mH[i][jj] = hh;
                *(float4*)&mE[i][jj] = en;
                mET[jj + 0][i] = en.x; mET[jj + 1][i] = en.y;
                mET[jj + 2][i] = en.z; mET[jj + 3][i] = en.w;
            }
            __syncthreads();
            // refresh register-resident E rows after the E rewrite
            LD_ROW16(mE, i, Er);
            LD_ROW16(mET, i, ETr);
        }
    }

    // ---- epilogue (verified math): P = L^-1, K = P W, Mc = A - K CA, Nb = B - K CB
    if (gq < 2) {
        const float4 l0 = *(const float4*)&mL[i][8 * gq];
        const float4 l1 = *(const float4*)&mL[i][8 * gq + 4];
        aug[0] = l0.x; aug[1] = l0.y; aug[2] = l0.z; aug[3] = l0.w;
        aug[4] = l1.x; aug[5] = l1.y; aug[6] = l1.z; aug[7] = l1.w;
    } else {
#pragma unroll
        for (int k = 0; k < 8; ++k) aug[k] = (8 * (gq - 2) + k == i) ? 1.f : 0.f;
    }
    gj16(aug, i, gq);
    if (gq >= 2) {
#pragma unroll
        for (int k = 0; k < 8; ++k) sP[i][8 * (gq - 2) + k] = aug[k];
    }
    __syncthreads();
#pragma unroll
    for (int m = 0; m < 8; ++m) {
        const int e = lane + 64 * m, ii = e >> 5, rr = e & 31;
        float s = 0.f;
#pragma unroll
        for (int q = 0; q < 16; ++q) s += sP[ii][q] * sW[q][rr];
        sK[ii][rr] = s;
        wsK[(size_t)t * 512 + e] = s;
    }
    __syncthreads();
#pragma unroll
    for (int m = 0; m < 4; ++m) {
        const int e = lane + 64 * m, ii = e >> 4, jjm = e & 15;
        float s = sAm[ii][jjm];
#pragma unroll
        for (int r = 0; r < 32; ++r) s -= sK[ii][r] * sCA[r][jjm];
        wsM[(size_t)t * 256 + e] = s;
    }
#pragma unroll
    for (int m = 0; m < 2; ++m) {
        const int e = lane + 64 * m, ii = e >> 3, jjm = e & 7;
        float s = sBm[ii][jjm];
#pragma unroll
        for (int r = 0; r < 32; ++r) s -= sK[ii][r] * sCB[r][jjm];
        wsN[(size_t)t * 128 + e] = s;
    }
}

// ---------------------------------------------------------------------------
// Phase A (verified R10-R12, unchanged).
// ---------------------------------------------------------------------------
__global__ __launch_bounds__(64) void phA_k(
    const float* __restrict__ u, const float* __restrict__ a,
    const float* __restrict__ wsK, const float* __restrict__ wsM,
    const float* __restrict__ wsN, float* __restrict__ wseg,
    float* __restrict__ wsp)
{
    const int lane = threadIdx.x;
    const int i = lane & 15, g = lane >> 4;
    const int seg = blockIdx.x >> 8;
    const int b = blockIdx.x & 255;

    float mcs[16][4];
#pragma unroll
    for (int j = 0; j < 16; ++j) {
        const int tc = (seg == 0) ? j : 16;
        const float4 v = *(const float4*)(wsM + (size_t)tc * 256 + i * 16 + 4 * g);
        mcs[j][0] = v.x; mcs[j][1] = v.y; mcs[j][2] = v.z; mcs[j][3] = v.w;
    }
    float kc[8], nbc[8];
    if (seg != 0) {
        const float4 k0 = *(const float4*)(wsK + (size_t)16 * 512 + i * 32 + 8 * g);
        const float4 k1 = *(const float4*)(wsK + (size_t)16 * 512 + i * 32 + 8 * g + 4);
        const float4 n0 = *(const float4*)(wsN + (size_t)16 * 128 + i * 8);
        const float4 n1 = *(const float4*)(wsN + (size_t)16 * 128 + i * 8 + 4);
        kc[0]=k0.x; kc[1]=k0.y; kc[2]=k0.z; kc[3]=k0.w;
        kc[4]=k1.x; kc[5]=k1.y; kc[6]=k1.z; kc[7]=k1.w;
        nbc[0]=n0.x; nbc[1]=n0.y; nbc[2]=n0.z; nbc[3]=n0.w;
        nbc[4]=n1.x; nbc[5]=n1.y; nbc[6]=n1.z; nbc[7]=n1.w;
    }

    float w = 0.f;
#pragma unroll
    for (int j = 0; j < 16; ++j) {
        const int t = 16 * seg + j;
        float kr[8], nbr[8];
        if (seg == 0) {
            const float4 k0 = *(const float4*)(wsK + (size_t)j * 512 + i * 32 + 8 * g);
            const float4 k1 = *(const float4*)(wsK + (size_t)j * 512 + i * 32 + 8 * g + 4);
            const float4 n0 = *(const float4*)(wsN + (size_t)j * 128 + i * 8);
            const float4 n1 = *(const float4*)(wsN + (size_t)j * 128 + i * 8 + 4);
            kr[0]=k0.x; kr[1]=k0.y; kr[2]=k0.z; kr[3]=k0.w;
            kr[4]=k1.x; kr[5]=k1.y; kr[6]=k1.z; kr[7]=k1.w;
            nbr[0]=n0.x; nbr[1]=n0.y; nbr[2]=n0.z; nbr[3]=n0.w;
            nbr[4]=n1.x; nbr[5]=n1.y; nbr[6]=n1.z; nbr[7]=n1.w;
        } else {
#pragma unroll
            for (int k = 0; k < 8; ++k) { kr[k] = kc[k]; nbr[k] = nbc[k]; }
        }
        const float a0 = a[(size_t)b * (TT * 32) + t * 32 + (lane & 31)];
        const float u0 = u[(size_t)b * (TT * 8) + t * 8 + (lane & 7)];
        float gvp = kr[0] * __shfl(a0, 8*g+0) + kr[1] * __shfl(a0, 8*g+1)
                  + kr[2] * __shfl(a0, 8*g+2) + kr[3] * __shfl(a0, 8*g+3)
                  + kr[4] * __shfl(a0, 8*g+4) + kr[5] * __shfl(a0, 8*g+5)
                  + kr[6] * __shfl(a0, 8*g+6) + kr[7] * __shfl(a0, 8*g+7);
        float nbs = nbr[0] * __shfl(u0,0) + nbr[1] * __shfl(u0,1)
                  + nbr[2] * __shfl(u0,2) + nbr[3] * __shfl(u0,3)
                  + nbr[4] * __shfl(u0,4) + nbr[5] * __shfl(u0,5)
                  + nbr[6] * __shfl(u0,6) + nbr[7] * __shfl(u0,7);
        gvp += (g == 3) ? nbs : 0.f;
        gvp += __shfl_xor(gvp, 16);
        gvp += __shfl_xor(gvp, 32);
        float part = mcs[j][0] * __shfl(w, 4*g+0) + mcs[j][1] * __shfl(w, 4*g+1)
                   + mcs[j][2] * __shfl(w, 4*g+2) + mcs[j][3] * __shfl(w, 4*g+3);
        part += __shfl_xor(part, 16);
        part += __shfl_xor(part, 32);
        w = part + gvp;
    }
    if (lane < 16) wseg[(size_t)seg * 4096 + b * 16 + i] = w;

    if (blockIdx.x == 0) {          // P0 = Mc15 ... Mc0
        float pr[4];
#pragma unroll
        for (int k = 0; k < 4; ++k) pr[k] = (4 * g + k == i) ? 1.f : 0.f;
#pragma unroll
        for (int j = 0; j < 16; ++j) {
            float np[4] = {0.f, 0.f, 0.f, 0.f};
#pragma unroll
            for (int q = 0; q < 16; ++q) {
                const float mq = __shfl(mcs[j][q & 3], i + 16 * (q >> 2));
#pragma unroll
                for (int k = 0; k < 4; ++k) np[k] += mq * __shfl(pr[k], q + 16 * g);
            }
#pragma unroll
            for (int k = 0; k < 4; ++k) pr[k] = np[k];
        }
#pragma unroll
        for (int k = 0; k < 4; ++k) wsp[i * 16 + 4 * g + k] = pr[k];
    }
    if (blockIdx.x == 256) {        // PP = Mc16^16
        float pr[4];
#pragma unroll
        for (int k = 0; k < 4; ++k) pr[k] = mcs[0][k];
#pragma unroll
        for (int r = 0; r < 4; ++r) {
            float np[4] = {0.f, 0.f, 0.f, 0.f};
#pragma unroll
            for (int q = 0; q < 16; ++q) {
                const float sq = __shfl(pr[q & 3], i + 16 * (q >> 2));
#pragma unroll
                for (int k = 0; k < 4; ++k) np[k] += sq * __shfl(pr[k], q + 16 * g);
            }
#pragma unroll
            for (int k = 0; k < 4; ++k) pr[k] = np[k];
        }
#pragma unroll
        for (int k = 0; k < 4; ++k) wsp[256 + i * 16 + 4 * g + k] = pr[k];
    }
}

// ---------------------------------------------------------------------------
// Phase B (verified R9-R12, unchanged).
// ---------------------------------------------------------------------------
__global__ __launch_bounds__(64) void phB_k(
    const float* __restrict__ mean0, const float* __restrict__ wsp,
    const float* __restrict__ wseg, float* __restrict__ bnd)
{
    const int lane = threadIdx.x;
    const int i = lane & 15, g = lane >> 4;
    const int b = blockIdx.x;

    const float4 v0 = *(const float4*)(wsp + i * 16 + 4 * g);
    const float4 vp = *(const float4*)(wsp + 256 + i * 16 + 4 * g);
    const float m0s[4] = {v0.x, v0.y, v0.z, v0.w};
    const float mps[4] = {vp.x, vp.y, vp.z, vp.w};
    float wv[16];
#pragma unroll
    for (int s = 0; s < 16; ++s) wv[s] = wseg[(size_t)s * 4096 + b * 16 + i];

    float mn = mean0[b * 16 + i];
#pragma unroll
    for (int s = 0; s < 16; ++s) {
        if (lane < 16) bnd[(size_t)s * 4096 + b * 16 + i] = mn;
        const float c0 = (s == 0) ? m0s[0] : mps[0];
        const float c1 = (s == 0) ? m0s[1] : mps[1];
        const float c2 = (s == 0) ? m0s[2] : mps[2];
        const float c3 = (s == 0) ? m0s[3] : mps[3];
        float part = c0 * __shfl(mn, 4 * g + 0) + c1 * __shfl(mn, 4 * g + 1)
                   + c2 * __shfl(mn, 4 * g + 2) + c3 * __shfl(mn, 4 * g + 3);
        part += __shfl_xor(part, 16);
        part += __shfl_xor(part, 32);
        mn = part + wv[s];
    }
}

// ---------------------------------------------------------------------------
// Phase C (verified R10-R12, unchanged).
// ---------------------------------------------------------------------------
__global__ __launch_bounds__(64) void phC_k(
    const float* __restrict__ u, const float* __restrict__ a,
    const float* __restrict__ wsK, const float* __restrict__ wsM,
    const float* __restrict__ wsN, const float* __restrict__ bnd,
    float* __restrict__ out)
{
    const int lane = threadIdx.x;
    const int i = lane & 15, g = lane >> 4;
    const int seg = blockIdx.x >> 8;
    const int b = blockIdx.x & 255;

    float mcs[16][4];
#pragma unroll
    for (int j = 0; j < 16; ++j) {
        const int tc = (seg == 0) ? j : 16;
        const float4 v = *(const float4*)(wsM + (size_t)tc * 256 + i * 16 + 4 * g);
        mcs[j][0] = v.x; mcs[j][1] = v.y; mcs[j][2] = v.z; mcs[j][3] = v.w;
    }
    float kc[8], nbc[8];
    if (seg != 0) {
        const float4 k0 = *(const float4*)(wsK + (size_t)16 * 512 + i * 32 + 8 * g);
        const float4 k1 = *(const float4*)(wsK + (size_t)16 * 512 + i * 32 + 8 * g + 4);
        const float4 n0 = *(const float4*)(wsN + (size_t)16 * 128 + i * 8);
        const float4 n1 = *(const float4*)(wsN + (size_t)16 * 128 + i * 8 + 4);
        kc[0]=k0.x; kc[1]=k0.y; kc[2]=k0.z; kc[3]=k0.w;
        kc[4]=k1.x; kc[5]=k1.y; kc[6]=k1.z; kc[7]=k1.w;
        nbc[0]=n0.x; nbc[1]=n0.y; nbc[2]=n0.z; nbc[3]=n0.w;
        nbc[4]=n1.x; nbc[5]=n1.y; nbc[6]=n1.z; nbc[7]=n1.w;
    }

    float mn = bnd[(size_t)seg * 4096 + b * 16 + i];
    float* ob = out + (size_t)b * 4096 + (size_t)(16 * seg) * 16;
#pragma unroll
    for (int j = 0; j < 16; ++j) {
        const int t = 16 * seg + j;
        float kr[8], nbr[8];
        if (seg == 0) {
            const float4 k0 = *(const float4*)(wsK + (size_t)j * 512 + i * 32 + 8 * g);
            const float4 k1 = *(const float4*)(wsK + (size_t)j * 512 + i * 32 + 8 * g + 4);
            const float4 n0 = *(const float4*)(wsN + (size_t)j * 128 + i * 8);
            const float4 n1 = *(const float4*)(wsN + (size_t)j * 128 + i * 8 + 4);
            kr[0]=k0.x; kr[1]=k0.y; kr[2]=k0.z; kr[3]=k0.w;
            kr[4]=k1.x; kr[5]=k1.y; kr[6]=k1.z; kr[7]=k1.w;
            nbr[0]=n0.x; nbr[1]=n0.y; nbr[2]=n0.z; nbr[3]=n0.w;
            nbr[4]=n1.x; nbr[5]=n1.y; nbr[6]=n1.z; nbr[7]=n1.w;
        } else {
#pragma unroll
            for (int k = 0; k < 8; ++k) { kr[k] = kc[k]; nbr[k] = nbc[k]; }
        }
        const float a0 = a[(size_t)b * (TT * 32) + t * 32 + (lane & 31)];
        const float u0 = u[(size_t)b * (TT * 8) + t * 8 + (lane & 7)];
        float gvp = kr[0] * __shfl(a0, 8*g+0) + kr[1] * __shfl(a0, 8*g+1)
                  + kr[2] * __shfl(a0, 8*g+2) + kr[3] * __shfl(a0, 8*g+3)
                  + kr[4] * __shfl(a0, 8*g+4) + kr[5] * __shfl(a0, 8*g+5)
                  + kr[6] * __shfl(a0, 8*g+6) + kr[7] * __shfl(a0, 8*g+7);
        float nbs = nbr[0] * __shfl(u0,0) + nbr[1] * __shfl(u0,1)
                  + nbr[2] * __shfl(u0,2) + nbr[3] * __shfl(u0,3)
                  + nbr[4] * __shfl(u0,4) + nbr[5] * __shfl(u0,5)
                  + nbr[6] * __shfl(u0,6) + nbr[7] * __shfl(u0,7);
        gvp += (g == 3) ? nbs : 0.f;
        gvp += __shfl_xor(gvp, 16);
        gvp += __shfl_xor(gvp, 32);
        float part = mcs[j][0] * __shfl(mn, 4*g+0) + mcs[j][1] * __shfl(mn, 4*g+1)
                   + mcs[j][2] * __shfl(mn, 4*g+2) + mcs[j][3] * __shfl(mn, 4*g+3);
        part += __shfl_xor(part, 16);
        part += __shfl_xor(part, 32);
        mn = part + gvp;
        if (lane < 16) ob[j * 16 + i] = mn;
    }
}

// ---------------------------------------------------------------------------
// Fallback (verified R6/R8/R9, unchanged): serial mean pass if ws too small.
// ---------------------------------------------------------------------------
__global__ __launch_bounds__(64) void meanf_k(
    const float* __restrict__ mean0, const float* __restrict__ u,
    const float* __restrict__ a, const float* __restrict__ wsK,
    const float* __restrict__ wsM, const float* __restrict__ wsN,
    float* __restrict__ out)
{
    const int lane = threadIdx.x;
    const int b = blockIdx.x;
    const int i = lane & 15;
    const int g = lane >> 4;

    const float* ub = u + (size_t)b * TT * 8;
    const float* ab = a + (size_t)b * TT * 32;
    float* ob = out + (size_t)b * TT * 16;

    float mn = mean0[b * 16 + i];
    float Mc[16];
    {
        const float4* p = (const float4*)(wsM + i * 16);
        float4 x0 = p[0], x1 = p[1], x2 = p[2], x3 = p[3];
        Mc[0]=x0.x; Mc[1]=x0.y; Mc[2]=x0.z; Mc[3]=x0.w;
        Mc[4]=x1.x; Mc[5]=x1.y; Mc[6]=x1.z; Mc[7]=x1.w;
        Mc[8]=x2.x; Mc[9]=x2.y; Mc[10]=x2.z; Mc[11]=x2.w;
        Mc[12]=x3.x; Mc[13]=x3.y; Mc[14]=x3.z; Mc[15]=x3.w;
    }
    float gv;
    {
        float4 k0 = *(const float4*)(wsK + i * 32 + 8 * g);
        float4 k1 = *(const float4*)(wsK + i * 32 + 8 * g + 4);
        float4 n0 = *(const float4*)(wsN + i * 8);
        float4 n1 = *(const float4*)(wsN + i * 8 + 4);
        float u0 = ub[lane & 7];
        float a0 = ab[lane & 31];
        float part = k0.x * __shfl(a0, 8*g+0) + k0.y * __shfl(a0, 8*g+1)
                   + k0.z * __shfl(a0, 8*g+2) + k0.w * __shfl(a0, 8*g+3)
                   + k1.x * __shfl(a0, 8*g+4) + k1.y * __shfl(a0, 8*g+5)
                   + k1.z * __shfl(a0, 8*g+6) + k1.w * __shfl(a0, 8*g+7);
        float nbs = n0.x * __shfl(u0,0) + n0.y * __shfl(u0,1)
                  + n0.z * __shfl(u0,2) + n0.w * __shfl(u0,3)
                  + n1.x * __shfl(u0,4) + n1.y * __shfl(u0,5)
                  + n1.z * __shfl(u0,6) + n1.w * __shfl(u0,7);
        part += (g == 3) ? nbs : 0.f;
        part += __shfl_xor(part, 16);
        part += __shfl_xor(part, 32);
        gv = part;
    }
    float4 mA, mB, mC, mD, kp0, kp1, np0, np1;
    float upn, apn;
    {
        const float4* p = (const float4*)(wsM + 256 + i * 16);
        mA = p[0]; mB = p[1]; mC = p[2]; mD = p[3];
        kp0 = *(const float4*)(wsK + 512 + i * 32 + 8 * g);
        kp1 = *(const float4*)(wsK + 512 + i * 32 + 8 * g + 4);
        np0 = *(const float4*)(wsN + 128 + i * 8);
        np1 = *(const float4*)(wsN + 128 + i * 8 + 4);
        upn = ub[8 + (lane & 7)];
        apn = ab[32 + (lane & 31)];
    }

    for (int t = 0; t < TT; ++t) {
        const int t2 = (t + 2 < TT) ? t + 2 : TT - 1;
        const int s2 = (t2 < WARM) ? t2 : WARM;
        const float4* mp = (const float4*)(wsM + (size_t)s2 * 256 + i * 16);
        float4 l0 = mp[0], l1 = mp[1], l2 = mp[2], l3 = mp[3];
        float4 kl0 = *(const float4*)(wsK + (size_t)s2 * 512 + i * 32 + 8 * g);
        float4 kl1 = *(const float4*)(wsK + (size_t)s2 * 512 + i * 32 + 8 * g + 4);
        float4 nl0 = *(const float4*)(wsN + (size_t)s2 * 128 + i * 8);
        float4 nl1 = *(const float4*)(wsN + (size_t)s2 * 128 + i * 8 + 4);
        float ul = ub[t2 * 8 + (lane & 7)];
        float al = ab[t2 * 32 + (lane & 31)];

        float s0 = gv, s1 = 0.f, s2f = 0.f, s3 = 0.f;
#pragma unroll
        for (int q = 0; q < 16; q += 4) {
            s0  += Mc[q]     * __shfl(mn, q);
            s1  += Mc[q + 1] * __shfl(mn, q + 1);
            s2f += Mc[q + 2] * __shfl(mn, q + 2);
            s3  += Mc[q + 3] * __shfl(mn, q + 3);
        }
        mn = (s0 + s1) + (s2f + s3);
        if (lane < 16) ob[t * 16 + lane] = mn;

        float part = kp0.x * __shfl(apn, 8*g+0) + kp0.y * __shfl(apn, 8*g+1)
                   + kp0.z * __shfl(apn, 8*g+2) + kp0.w * __shfl(apn, 8*g+3)
                   + kp1.x * __shfl(apn, 8*g+4) + kp1.y * __shfl(apn, 8*g+5)
                   + kp1.z * __shfl(apn, 8*g+6) + kp1.w * __shfl(apn, 8*g+7);
        float nbs = np0.x * __shfl(upn,0) + np0.y * __shfl(upn,1)
                  + np0.z * __shfl(upn,2) + np0.w * __shfl(upn,3)
                  + np1.x * __shfl(upn,4) + np1.y * __shfl(upn,5)
                  + np1.z * __shfl(upn,6) + np1.w * __shfl(upn,7);
        part += (g == 3) ? nbs : 0.f;
        part += __shfl_xor(part, 16);
        part += __shfl_xor(part, 32);
        gv = part;

        Mc[0]=mA.x; Mc[1]=mA.y; Mc[2]=mA.z; Mc[3]=mA.w;
        Mc[4]=mB.x; Mc[5]=mB.y; Mc[6]=mB.z; Mc[7]=mB.w;
        Mc[8]=mC.x; Mc[9]=mC.y; Mc[10]=mC.z; Mc[11]=mC.w;
        Mc[12]=mD.x; Mc[13]=mD.y; Mc[14]=mD.z; Mc[15]=mD.w;
        mA = l0; mB = l1; mC = l2; mD = l3;
        kp0 = kl0; kp1 = kl1; np0 = nl0; np1 = nl1;
        upn = ul; apn = al;
    }
}

extern "C" void kernel_launch(void* const* d_in, const int* in_sizes, int n_in,
                              void* d_out, int out_size, void* d_ws, size_t ws_size,
                              hipStream_t stream) {
    const float* mean0 = nullptr; const float* cov0 = nullptr;
    const float* u = nullptr;     const float* a = nullptr;
    const float* Mm = nullptr;    const float* Nm = nullptr;
    const float* dv = nullptr;    const float* Bm = nullptr;
    const float* Cm = nullptr;    const float* nxp = nullptr;
    const float* nap = nullptr;
    for (int i = 0; i < n_in; ++i) {
        const float* p = (const float*)d_in[i];
        switch (in_sizes[i]) {
            case 256 * 16:        mean0 = p; break;
            case 256 * 256:       cov0 = p; break;
            case 256 * 256 * 8:   u = p; break;
            case 256 * 256 * 32:  a = p; break;
            case 256:             if (!Mm) Mm = p; else Nm = p; break;
            case 16:              if (!dv) dv = p; else nxp = p; break;
            case 128:             Bm = p; break;
            case 512:             Cm = p; break;
            case 32:              nap = p; break;
            default: break;
        }
    }
    float* ws   = (float*)d_ws;
    float* wsK  = ws + OFF_K;
    float* wsM  = ws + OFF_MC;
    float* wsN  = ws + OFF_NB;
    float* wsp  = ws + OFF_P0;
    float* wseg = ws + OFF_WSEG;
    float* bnd  = ws + OFF_BND;

    chain_k<<<WARM + 1, 64, 0, stream>>>(Mm, Nm, dv, Bm, Cm, nxp, nap, cov0,
                                         wsK, wsM, wsN);
    if (ws_size >= NEED_WS_BYTES) {
        phA_k<<<16 * 256, 64, 0, stream>>>(u, a, wsK, wsM, wsN, wseg, wsp);
        phB_k<<<256, 64, 0, stream>>>(mean0, wsp, wseg, bnd);
        phC_k<<<16 * 256, 64, 0, stream>>>(u, a, wsK, wsM, wsN, bnd, (float*)d_out);
    } else {
        meanf_k<<<256, 64, 0, stream>>>(mean0, u, a, wsK, wsM, wsN, (float*)d_out);
    }
}

// Round 3
// 164.089 us; speedup vs baseline: 1.3344x; 1.0768x over previous
//
#include <hip/hip_runtime.h>
#include <math.h>

#define TT 256
#define WARM 16
// ws float offsets (chain outputs + scan intermediates only)
#define OFF_K    5632   // 17 x 512 -> 14336
#define OFF_MC   14336  // 17 x 256 -> 18688
#define OFF_NB   18688  // 17 x 128 -> 20864
#define OFF_P0   20864  // Mseg0 (256) -> 21120
#define OFF_PP   21120  // Mc16^16 (256) -> 21376
#define OFF_WSEG 21376  // 16 x 256 x 16 -> 86912
#define OFF_BND  86912  // 16 x 256 x 16 -> 152448
#define OFF_GV   152448 // 256 x 256 x 16 -> 1201024
#define NEED_WS_BYTES ((size_t)152448 * 4)
#define NEED_WS2_BYTES ((size_t)1201024 * 4)

__device__ __forceinline__ float softplus(float v) {
    return fmaxf(v, 0.0f) + log1pf(expf(-fabsf(v)));
}

// Shuffle-based Gauss-Jordan, [X|I] -> [I|X^-1] (verified R5-R12).
// Layout: lane (i, gq) holds aug[i][8*gq+k], k=0..7.
// R16: j-loop rolled (#pragma unroll 1) to shrink I-footprint; gj16 is
// inlined 4x in chain_k and the unrolled form (~300 instrs each) likely
// blows the 32KiB I-cache with only 1 wave/CU to warm it.
__device__ __forceinline__ void gj16(float (&aug)[8], const int i, const int gq) {
#pragma unroll 1
    for (int j = 0; j < 16; ++j) {
        float prow[8];
#pragma unroll
        for (int k = 0; k < 8; ++k) prow[k] = __shfl(aug[k], j + 16 * gq);
        const float pjj = __shfl(aug[j & 7], j + 16 * (j >> 3));
        const float cij = __shfl(aug[j & 7], i + 16 * (j >> 3));
        const float pivinv = 1.0f / pjj;
        const float f = cij * pivinv;
#pragma unroll
        for (int k = 0; k < 8; ++k)
            aug[k] = (i == j) ? prow[k] * pivinv : aug[k] - f * prow[k];
    }
}

// Load a full 16-float row from a stride-20 LDS matrix into registers (4x b128).
#define LD_ROW16(Mt, r, row) do { \
    const float4 r0_ = *(const float4*)&Mt[r][0]; \
    const float4 r1_ = *(const float4*)&Mt[r][4]; \
    const float4 r2_ = *(const float4*)&Mt[r][8]; \
    const float4 r3_ = *(const float4*)&Mt[r][12]; \
    row[0]=r0_.x;  row[1]=r0_.y;  row[2]=r0_.z;  row[3]=r0_.w; \
    row[4]=r1_.x;  row[5]=r1_.y;  row[6]=r1_.z;  row[7]=r1_.w; \
    row[8]=r2_.x;  row[9]=r2_.y;  row[10]=r2_.z; row[11]=r2_.w; \
    row[12]=r3_.x; row[13]=r3_.y; row[14]=r3_.z; row[15]=r3_.w; } while (0)

// ---------------------------------------------------------------------------
// Fused chain kernel (R13 math, R15 data path, R16 rolled gj16).
// ---------------------------------------------------------------------------
__global__ __launch_bounds__(64) void chain_k(
    const float* __restrict__ Mm, const float* __restrict__ Nm,
    const float* __restrict__ dvec, const float* __restrict__ Bm,
    const float* __restrict__ Cm, const float* __restrict__ nx,
    const float* __restrict__ na, const float* __restrict__ cov0,
    float* __restrict__ wsK, float* __restrict__ wsM, float* __restrict__ wsN)
{
    __shared__ float qm[16][17], qn[16][17], T0s[16][17];
    __shared__ float sC[32][17], sW[16][33], sAm[16][17], sBm[16][9];
    __shared__ float sCA[32][17], sCB[32][9], sP[16][17], sK[16][33];
    __shared__ float spv[16], d2[16], sNai[32], sNxi[16];
    // stride-20 matmul arenas: rows are 80B apart -> float4-aligned, and
    // column accesses hit <=2-way bank aliasing (free).
    __shared__ __attribute__((aligned(16))) float mE[16][20];
    __shared__ __attribute__((aligned(16))) float mET[16][20];
    __shared__ __attribute__((aligned(16))) float mF[16][20];
    __shared__ __attribute__((aligned(16))) float mH[16][20];
    __shared__ __attribute__((aligned(16))) float mZ[16][20];
    __shared__ __attribute__((aligned(16))) float mT[16][20];
    __shared__ __attribute__((aligned(16))) float mT2[16][20];
    __shared__ __attribute__((aligned(16))) float mL[16][20];
    const int lane = threadIdx.x;
    const int t = blockIdx.x;            // 0..16
    const int n = t + 1;                 // steps to apply
    const int i = lane & 15, gq = lane >> 4;
    const int jj = gq << 2;              // 4-wide column chunk this lane owns

    // ---- load inputs ----
    for (int e = lane; e < 256; e += 64) { qm[e >> 4][e & 15] = Mm[e]; qn[e >> 4][e & 15] = Nm[e]; }
    for (int e = lane; e < 512; e += 64) sC[e >> 4][e & 15] = Cm[e];
    for (int e = lane; e < 128; e += 64) sBm[e >> 3][e & 7] = Bm[e];
    if (lane < 16) {
        float s = softplus(dvec[lane]);
        spv[lane] = sqrtf(s);
        d2[lane] = 1.0f / sqrtf(1.0f + s);
        sNxi[lane] = 1.0f / (softplus(nx[lane]) + 1e-4f);
    }
    if (lane < 32) sNai[lane] = 1.0f / (softplus(na[lane]) + 1e-4f);
    __syncthreads();

    // ---- register MGS QR on both matrices (verified R12, rolled) ----
    {
        const int j0 = lane & 15;
        const int mi = lane >> 4;
        float (*Qs)[17] = (mi == 1) ? qn : qm;
        float col[16];
#pragma unroll
        for (int r = 0; r < 16; ++r) col[r] = Qs[r][j0];
        const int base = lane & 48;
#pragma unroll 1
        for (int j = 0; j < 16; ++j) {
            float qj[16];
#pragma unroll
            for (int r = 0; r < 16; ++r) qj[r] = __shfl(col[r], base + j);
            float nrm = 0.f;
#pragma unroll
            for (int r = 0; r < 16; ++r) nrm += qj[r] * qj[r];
            const float scal = 1.0f / sqrtf(nrm);
#pragma unroll
            for (int r = 0; r < 16; ++r) qj[r] *= scal;
            if (j0 == j) {
#pragma unroll
                for (int r = 0; r < 16; ++r) col[r] = qj[r];
            } else if (j0 > j) {
                float pr = 0.f;
#pragma unroll
                for (int r = 0; r < 16; ++r) pr += qj[r] * col[r];
#pragma unroll
                for (int r = 0; r < 16; ++r) col[r] -= pr * qj[r];
            }
        }
        __syncthreads();
        if (mi < 2) {
#pragma unroll
            for (int r = 0; r < 16; ++r) Qs[r][j0] = col[r];
        }
    }
    __syncthreads();

    // ---- assembly: A, W, base map E/F/H, CA, CB (verified patterns) ----
    for (int e = lane; e < 256; e += 64) {
        int ii = e >> 4, j = e & 15;
        float s = 0.f;
        for (int q = 0; q < 16; ++q) s += qm[ii][q] * d2[q] * qn[j][q];
        T0s[ii][j] = spv[ii] * s;
    }
    __syncthreads();
    for (int e = lane; e < 256; e += 64) {
        int ii = e >> 4, j = e & 15;
        float s = 0.f;
        for (int q = 0; q < 16; ++q) s += qn[ii][q] * T0s[q][j];
        sAm[ii][j] = s;
    }
    for (int e = lane; e < 512; e += 64) {
        int q = e >> 5, r = e & 31;
        sW[q][r] = sC[r][q] * sNai[r];
    }
    __syncthreads();
    for (int e = lane; e < 256; e += 64) {
        int ii = e >> 4, j = e & 15;
        float g = 0.f;
        for (int r = 0; r < 32; ++r) g += sC[r][ii] * sW[j][r];
        mF[ii][j] = g + ((ii == j) ? sNxi[ii] : 0.f);
        const float ev = sNxi[ii] * sAm[ii][j];
        mE[ii][j] = ev;
        mET[j][ii] = ev;
        float hsum = 0.f;
        for (int q = 0; q < 16; ++q) hsum += sAm[q][ii] * sNxi[q] * sAm[q][j];
        mH[ii][j] = hsum;
    }
    for (int e = lane; e < 512; e += 64) {
        int r = e >> 4, j = e & 15;
        float s = 0.f;
        for (int q = 0; q < 16; ++q) s += sC[r][q] * sAm[q][j];
        sCA[r][j] = s;
    }
    for (int e = lane; e < 256; e += 64) {
        int r = e >> 3, j = e & 7;
        float s = 0.f;
        for (int q = 0; q < 16; ++q) s += sC[r][q] * sBm[q][j];
        sCB[r][j] = s;
    }
    __syncthreads();

    // ---- E rows register-resident across the m-loop (R13-style residency) ----
    float Er[16], ETr[16];
    LD_ROW16(mE, i, Er);
    LD_ROW16(mET, i, ETr);

    // ---- L0 = inv(cov0) -> mL ----
    float aug[8];
#pragma unroll
    for (int k = 0; k < 8; ++k)
        aug[k] = (gq < 2) ? cov0[i * 16 + 8 * gq + k]
                          : ((8 * (gq - 2) + k == i) ? 1.f : 0.f);
    gj16(aug, i, gq);
    if (gq >= 2) {
        *(float4*)&mL[i][8 * (gq - 2)]     = make_float4(aug[0], aug[1], aug[2], aug[3]);
        *(float4*)&mL[i][8 * (gq - 2) + 4] = make_float4(aug[4], aug[5], aug[6], aug[7]);
    }
    __syncthreads();

    // ---- interleaved LSB-first double-and-apply (batched-LDS matmuls) ----
#pragma unroll 1
    for (int m = 0; m < 5; ++m) {
        if ((n >> m) & 1) {
            // apply: L = F - E (L+H)^-1 E^T
            if (gq < 2) {
                const float4 l0 = *(const float4*)&mL[i][8 * gq];
                const float4 l1 = *(const float4*)&mL[i][8 * gq + 4];
                const float4 h0 = *(const float4*)&mH[i][8 * gq];
                const float4 h1 = *(const float4*)&mH[i][8 * gq + 4];
                aug[0] = l0.x + h0.x; aug[1] = l0.y + h0.y;
                aug[2] = l0.z + h0.z; aug[3] = l0.w + h0.w;
                aug[4] = l1.x + h1.x; aug[5] = l1.y + h1.y;
                aug[6] = l1.z + h1.z; aug[7] = l1.w + h1.w;
            } else {
#pragma unroll
                for (int k = 0; k < 8; ++k) aug[k] = (8 * (gq - 2) + k == i) ? 1.f : 0.f;
            }
            gj16(aug, i, gq);
            if (gq >= 2) {
                *(float4*)&mZ[i][8 * (gq - 2)]     = make_float4(aug[0], aug[1], aug[2], aug[3]);
                *(float4*)&mZ[i][8 * (gq - 2) + 4] = make_float4(aug[4], aug[5], aug[6], aug[7]);
            }
            __syncthreads();
            // T = E * Z : batch ALL column loads first, then FMA
            {
                float4 zz[16];
#pragma unroll
                for (int q = 0; q < 16; ++q) zz[q] = *(const float4*)&mZ[q][jj];
                float4 tacc = make_float4(0.f, 0.f, 0.f, 0.f);
#pragma unroll
                for (int q = 0; q < 16; ++q) {
                    tacc.x += Er[q] * zz[q].x; tacc.y += Er[q] * zz[q].y;
                    tacc.z += Er[q] * zz[q].z; tacc.w += Er[q] * zz[q].w;
                }
                *(float4*)&mT[i][jj] = tacc;
            }
            __syncthreads();
            // L' = F - T * E^T : batch T-row + all ET columns, then FMA
            {
                float Tr[16];
                LD_ROW16(mT, i, Tr);
                float4 et[16];
#pragma unroll
                for (int q = 0; q < 16; ++q) et[q] = *(const float4*)&mET[q][jj];
                float4 l = *(const float4*)&mF[i][jj];
#pragma unroll
                for (int q = 0; q < 16; ++q) {
                    l.x -= Tr[q] * et[q].x; l.y -= Tr[q] * et[q].y;
                    l.z -= Tr[q] * et[q].z; l.w -= Tr[q] * et[q].w;
                }
                __syncthreads();
                *(float4*)&mL[i][jj] = l;
            }
            __syncthreads();
        }
        if (m < 4 && (n >> (m + 1)) != 0) {
            // double: Z=(F+H)^-1, T=EZ, T2=E^T Z, F'=F-T E^T, H'=H-T2 E, E'=T E
            if (gq < 2) {
                const float4 f0 = *(const float4*)&mF[i][8 * gq];
                const float4 f1 = *(const float4*)&mF[i][8 * gq + 4];
                const float4 h0 = *(const float4*)&mH[i][8 * gq];
                const float4 h1 = *(const float4*)&mH[i][8 * gq + 4];
                aug[0] = f0.x + h0.x; aug[1] = f0.y + h0.y;
                aug[2] = f0.z + h0.z; aug[3] = f0.w + h0.w;
                aug[4] = f1.x + h1.x; aug[5] = f1.y + h1.y;
                aug[6] = f1.z + h1.z; aug[7] = f1.w + h1.w;
            } else {
#pragma unroll
                for (int k = 0; k < 8; ++k) aug[k] = (8 * (gq - 2) + k == i) ? 1.f : 0.f;
            }
            gj16(aug, i, gq);
            if (gq >= 2) {
                *(float4*)&mZ[i][8 * (gq - 2)]     = make_float4(aug[0], aug[1], aug[2], aug[3]);
                *(float4*)&mZ[i][8 * (gq - 2) + 4] = make_float4(aug[4], aug[5], aug[6], aug[7]);
            }
            __syncthreads();
            // T = E*Z, T2 = E^T*Z : batch Z columns once, share
            {
                float4 zz[16];
#pragma unroll
                for (int q = 0; q < 16; ++q) zz[q] = *(const float4*)&mZ[q][jj];
                float4 tacc = make_float4(0.f, 0.f, 0.f, 0.f);
                float4 t2acc = make_float4(0.f, 0.f, 0.f, 0.f);
#pragma unroll
                for (int q = 0; q < 16; ++q) {
                    tacc.x  += Er[q]  * zz[q].x; tacc.y  += Er[q]  * zz[q].y;
                    tacc.z  += Er[q]  * zz[q].z; tacc.w  += Er[q]  * zz[q].w;
                    t2acc.x += ETr[q] * zz[q].x; t2acc.y += ETr[q] * zz[q].y;
                    t2acc.z += ETr[q] * zz[q].z; t2acc.w += ETr[q] * zz[q].w;
                }
                *(float4*)&mT[i][jj]  = tacc;
                *(float4*)&mT2[i][jj] = t2acc;
            }
            __syncthreads();
            // F' = F - T*E^T ; H' = H - T2*E ; E' = T*E   (E cols in halves of 8)
            {
                float Tr[16], T2r[16];
                LD_ROW16(mT, i, Tr);
                LD_ROW16(mT2, i, T2r);
                float4 f  = *(const float4*)&mF[i][jj];
                float4 hh = *(const float4*)&mH[i][jj];
                float4 en = make_float4(0.f, 0.f, 0.f, 0.f);
#pragma unroll
                for (int qh = 0; qh < 16; qh += 8) {
                    float4 eq[8], etq[8];
#pragma unroll
                    for (int q0 = 0; q0 < 8; ++q0) {
                        eq[q0]  = *(const float4*)&mE[qh + q0][jj];
                        etq[q0] = *(const float4*)&mET[qh + q0][jj];
                    }
#pragma unroll
                    for (int q0 = 0; q0 < 8; ++q0) {
                        const float tq = Tr[qh + q0], t2q = T2r[qh + q0];
                        f.x  -= tq  * etq[q0].x; f.y  -= tq  * etq[q0].y;
                        f.z  -= tq  * etq[q0].z; f.w  -= tq  * etq[q0].w;
                        hh.x -= t2q * eq[q0].x;  hh.y -= t2q * eq[q0].y;
                        hh.z -= t2q * eq[q0].z;  hh.w -= t2q * eq[q0].w;
                        en.x += tq  * eq[q0].x;  en.y += tq  * eq[q0].y;
                        en.z += tq  * eq[q0].z;  en.w += tq  * eq[q0].w;
                    }
                }
                __syncthreads();   // all reads of E/ET/F/H done before overwrite
                *(float4*)&mF[i][jj] = f;
                *(float4*)&mH[i][jj] = hh;
                *(float4*)&mE[i][jj] = en;
                mET[jj + 0][i] = en.x; mET[jj + 1][i] = en.y;
                mET[jj + 2][i] = en.z; mET[jj + 3][i] = en.w;
            }
            __syncthreads();
            // refresh register-resident E rows after the E rewrite
            LD_ROW16(mE, i, Er);
            LD_ROW16(mET, i, ETr);
        }
    }

    // ---- epilogue (verified math): P = L^-1, K = P W, Mc = A - K CA, Nb = B - K CB
    if (gq < 2) {
        const float4 l0 = *(const float4*)&mL[i][8 * gq];
        const float4 l1 = *(const float4*)&mL[i][8 * gq + 4];
        aug[0] = l0.x; aug[1] = l0.y; aug[2] = l0.z; aug[3] = l0.w;
        aug[4] = l1.x; aug[5] = l1.y; aug[6] = l1.z; aug[7] = l1.w;
    } else {
#pragma unroll
        for (int k = 0; k < 8; ++k) aug[k] = (8 * (gq - 2) + k == i) ? 1.f : 0.f;
    }
    gj16(aug, i, gq);
    if (gq >= 2) {
#pragma unroll
        for (int k = 0; k < 8; ++k) sP[i][8 * (gq - 2) + k] = aug[k];
    }
    __syncthreads();
#pragma unroll
    for (int m = 0; m < 8; ++m) {
        const int e = lane + 64 * m, ii = e >> 5, rr = e & 31;
        float s = 0.f;
#pragma unroll
        for (int q = 0; q < 16; ++q) s += sP[ii][q] * sW[q][rr];
        sK[ii][rr] = s;
        wsK[(size_t)t * 512 + e] = s;
    }
    __syncthreads();
#pragma unroll
    for (int m = 0; m < 4; ++m) {
        const int e = lane + 64 * m, ii = e >> 4, jjm = e & 15;
        float s = sAm[ii][jjm];
#pragma unroll
        for (int r = 0; r < 32; ++r) s -= sK[ii][r] * sCA[r][jjm];
        wsM[(size_t)t * 256 + e] = s;
    }
#pragma unroll
    for (int m = 0; m < 2; ++m) {
        const int e = lane + 64 * m, ii = e >> 3, jjm = e & 7;
        float s = sBm[ii][jjm];
#pragma unroll
        for (int r = 0; r < 32; ++r) s -= sK[ii][r] * sCB[r][jjm];
        wsN[(size_t)t * 128 + e] = s;
    }
}

// ---------------------------------------------------------------------------
// Phase A v2 (R16): gvp via DIRECT vector loads of a/u (no lane broadcasts;
// 16 bpermutes/step removed) and stores reduced gv[t][b][i] to ws so phC
// doesn't recompute it. Scan math identical to verified R10-R12 phA.
// ---------------------------------------------------------------------------
__global__ __launch_bounds__(64) void phA_k(
    const float* __restrict__ u, const float* __restrict__ a,
    const float* __restrict__ wsK, const float* __restrict__ wsM,
    const float* __restrict__ wsN, float* __restrict__ wseg,
    float* __restrict__ wsp, float* __restrict__ gv)
{
    const int lane = threadIdx.x;
    const int i = lane & 15, g = lane >> 4;
    const int seg = blockIdx.x >> 8;
    const int b = blockIdx.x & 255;

    float mcs[16][4];
#pragma unroll
    for (int j = 0; j < 16; ++j) {
        const int tc = (seg == 0) ? j : 16;
        const float4 v = *(const float4*)(wsM + (size_t)tc * 256 + i * 16 + 4 * g);
        mcs[j][0] = v.x; mcs[j][1] = v.y; mcs[j][2] = v.z; mcs[j][3] = v.w;
    }
    float kc[8], nbc[8];
    if (seg != 0) {
        const float4 k0 = *(const float4*)(wsK + (size_t)16 * 512 + i * 32 + 8 * g);
        const float4 k1 = *(const float4*)(wsK + (size_t)16 * 512 + i * 32 + 8 * g + 4);
        const float4 n0 = *(const float4*)(wsN + (size_t)16 * 128 + i * 8);
        const float4 n1 = *(const float4*)(wsN + (size_t)16 * 128 + i * 8 + 4);
        kc[0]=k0.x; kc[1]=k0.y; kc[2]=k0.z; kc[3]=k0.w;
        kc[4]=k1.x; kc[5]=k1.y; kc[6]=k1.z; kc[7]=k1.w;
        nbc[0]=n0.x; nbc[1]=n0.y; nbc[2]=n0.z; nbc[3]=n0.w;
        nbc[4]=n1.x; nbc[5]=n1.y; nbc[6]=n1.z; nbc[7]=n1.w;
    }

    float w = 0.f;
#pragma unroll
    for (int j = 0; j < 16; ++j) {
        const int t = 16 * seg + j;
        float kr[8], nbr[8];
        if (seg == 0) {
            const float4 k0 = *(const float4*)(wsK + (size_t)j * 512 + i * 32 + 8 * g);
            const float4 k1 = *(const float4*)(wsK + (size_t)j * 512 + i * 32 + 8 * g + 4);
            const float4 n0 = *(const float4*)(wsN + (size_t)j * 128 + i * 8);
            const float4 n1 = *(const float4*)(wsN + (size_t)j * 128 + i * 8 + 4);
            kr[0]=k0.x; kr[1]=k0.y; kr[2]=k0.z; kr[3]=k0.w;
            kr[4]=k1.x; kr[5]=k1.y; kr[6]=k1.z; kr[7]=k1.w;
            nbr[0]=n0.x; nbr[1]=n0.y; nbr[2]=n0.z; nbr[3]=n0.w;
            nbr[4]=n1.x; nbr[5]=n1.y; nbr[6]=n1.z; nbr[7]=n1.w;
        } else {
#pragma unroll
            for (int k = 0; k < 8; ++k) { kr[k] = kc[k]; nbr[k] = nbc[k]; }
        }
        // direct vector loads: lane (i,g) needs a[b][t][8g..8g+7], u[b][t][0..7]
        const float4 av0 = *(const float4*)(a + (size_t)b * (TT * 32) + t * 32 + 8 * g);
        const float4 av1 = *(const float4*)(a + (size_t)b * (TT * 32) + t * 32 + 8 * g + 4);
        const float4 uv0 = *(const float4*)(u + (size_t)b * (TT * 8) + t * 8);
        const float4 uv1 = *(const float4*)(u + (size_t)b * (TT * 8) + t * 8 + 4);
        float gvp = kr[0] * av0.x + kr[1] * av0.y + kr[2] * av0.z + kr[3] * av0.w
                  + kr[4] * av1.x + kr[5] * av1.y + kr[6] * av1.z + kr[7] * av1.w;
        float nbs = nbr[0] * uv0.x + nbr[1] * uv0.y + nbr[2] * uv0.z + nbr[3] * uv0.w
                  + nbr[4] * uv1.x + nbr[5] * uv1.y + nbr[6] * uv1.z + nbr[7] * uv1.w;
        gvp += (g == 3) ? nbs : 0.f;
        gvp += __shfl_xor(gvp, 16);
        gvp += __shfl_xor(gvp, 32);
        if (lane < 16) gv[(size_t)t * 4096 + b * 16 + i] = gvp;
        float part = mcs[j][0] * __shfl(w, 4*g+0) + mcs[j][1] * __shfl(w, 4*g+1)
                   + mcs[j][2] * __shfl(w, 4*g+2) + mcs[j][3] * __shfl(w, 4*g+3);
        part += __shfl_xor(part, 16);
        part += __shfl_xor(part, 32);
        w = part + gvp;
    }
    if (lane < 16) wseg[(size_t)seg * 4096 + b * 16 + i] = w;

    if (blockIdx.x == 0) {          // P0 = Mc15 ... Mc0
        float pr[4];
#pragma unroll
        for (int k = 0; k < 4; ++k) pr[k] = (4 * g + k == i) ? 1.f : 0.f;
#pragma unroll
        for (int j = 0; j < 16; ++j) {
            float np[4] = {0.f, 0.f, 0.f, 0.f};
#pragma unroll
            for (int q = 0; q < 16; ++q) {
                const float mq = __shfl(mcs[j][q & 3], i + 16 * (q >> 2));
#pragma unroll
                for (int k = 0; k < 4; ++k) np[k] += mq * __shfl(pr[k], q + 16 * g);
            }
#pragma unroll
            for (int k = 0; k < 4; ++k) pr[k] = np[k];
        }
#pragma unroll
        for (int k = 0; k < 4; ++k) wsp[i * 16 + 4 * g + k] = pr[k];
    }
    if (blockIdx.x == 256) {        // PP = Mc16^16
        float pr[4];
#pragma unroll
        for (int k = 0; k < 4; ++k) pr[k] = mcs[0][k];
#pragma unroll
        for (int r = 0; r < 4; ++r) {
            float np[4] = {0.f, 0.f, 0.f, 0.f};
#pragma unroll
            for (int q = 0; q < 16; ++q) {
                const float sq = __shfl(pr[q & 3], i + 16 * (q >> 2));
#pragma unroll
                for (int k = 0; k < 4; ++k) np[k] += sq * __shfl(pr[k], q + 16 * g);
            }
#pragma unroll
            for (int k = 0; k < 4; ++k) pr[k] = np[k];
        }
#pragma unroll
        for (int k = 0; k < 4; ++k) wsp[256 + i * 16 + 4 * g + k] = pr[k];
    }
}

// ---------------------------------------------------------------------------
// Phase B (verified R9-R12, unchanged).
// ---------------------------------------------------------------------------
__global__ __launch_bounds__(64) void phB_k(
    const float* __restrict__ mean0, const float* __restrict__ wsp,
    const float* __restrict__ wseg, float* __restrict__ bnd)
{
    const int lane = threadIdx.x;
    const int i = lane & 15, g = lane >> 4;
    const int b = blockIdx.x;

    const float4 v0 = *(const float4*)(wsp + i * 16 + 4 * g);
    const float4 vp = *(const float4*)(wsp + 256 + i * 16 + 4 * g);
    const float m0s[4] = {v0.x, v0.y, v0.z, v0.w};
    const float mps[4] = {vp.x, vp.y, vp.z, vp.w};
    float wv[16];
#pragma unroll
    for (int s = 0; s < 16; ++s) wv[s] = wseg[(size_t)s * 4096 + b * 16 + i];

    float mn = mean0[b * 16 + i];
#pragma unroll
    for (int s = 0; s < 16; ++s) {
        if (lane < 16) bnd[(size_t)s * 4096 + b * 16 + i] = mn;
        const float c0 = (s == 0) ? m0s[0] : mps[0];
        const float c1 = (s == 0) ? m0s[1] : mps[1];
        const float c2 = (s == 0) ? m0s[2] : mps[2];
        const float c3 = (s == 0) ? m0s[3] : mps[3];
        float part = c0 * __shfl(mn, 4 * g + 0) + c1 * __shfl(mn, 4 * g + 1)
                   + c2 * __shfl(mn, 4 * g + 2) + c3 * __shfl(mn, 4 * g + 3);
        part += __shfl_xor(part, 16);
        part += __shfl_xor(part, 32);
        mn = part + wv[s];
    }
}

// ---------------------------------------------------------------------------
// Phase C v2 (R16): loads precomputed gv[t][b][i] (from phA) instead of
// recomputing K a_t + Nb u_t. Scan math identical to verified phC.
// ---------------------------------------------------------------------------
__global__ __launch_bounds__(64) void phC_k(
    const float* __restrict__ wsM, const float* __restrict__ gv,
    const float* __restrict__ bnd, float* __restrict__ out)
{
    const int lane = threadIdx.x;
    const int i = lane & 15, g = lane >> 4;
    const int seg = blockIdx.x >> 8;
    const int b = blockIdx.x & 255;

    float mcs[16][4];
#pragma unroll
    for (int j = 0; j < 16; ++j) {
        const int tc = (seg == 0) ? j : 16;
        const float4 v = *(const float4*)(wsM + (size_t)tc * 256 + i * 16 + 4 * g);
        mcs[j][0] = v.x; mcs[j][1] = v.y; mcs[j][2] = v.z; mcs[j][3] = v.w;
    }
    float gvr[16];
#pragma unroll
    for (int j = 0; j < 16; ++j)
        gvr[j] = gv[(size_t)(16 * seg + j) * 4096 + b * 16 + i];

    float mn = bnd[(size_t)seg * 4096 + b * 16 + i];
    float* ob = out + (size_t)b * 4096 + (size_t)(16 * seg) * 16;
#pragma unroll
    for (int j = 0; j < 16; ++j) {
        float part = mcs[j][0] * __shfl(mn, 4*g+0) + mcs[j][1] * __shfl(mn, 4*g+1)
                   + mcs[j][2] * __shfl(mn, 4*g+2) + mcs[j][3] * __shfl(mn, 4*g+3);
        part += __shfl_xor(part, 16);
        part += __shfl_xor(part, 32);
        mn = part + gvr[j];
        if (lane < 16) ob[j * 16 + i] = mn;
    }
}

// ---------------------------------------------------------------------------
// Phase A (verified R10-R12, original form) — fallback when ws fits the old
// layout but not the gv buffer.
// ---------------------------------------------------------------------------
__global__ __launch_bounds__(64) void phAo_k(
    const float* __restrict__ u, const float* __restrict__ a,
    const float* __restrict__ wsK, const float* __restrict__ wsM,
    const float* __restrict__ wsN, float* __restrict__ wseg,
    float* __restrict__ wsp)
{
    const int lane = threadIdx.x;
    const int i = lane & 15, g = lane >> 4;
    const int seg = blockIdx.x >> 8;
    const int b = blockIdx.x & 255;

    float mcs[16][4];
#pragma unroll
    for (int j = 0; j < 16; ++j) {
        const int tc = (seg == 0) ? j : 16;
        const float4 v = *(const float4*)(wsM + (size_t)tc * 256 + i * 16 + 4 * g);
        mcs[j][0] = v.x; mcs[j][1] = v.y; mcs[j][2] = v.z; mcs[j][3] = v.w;
    }
    float kc[8], nbc[8];
    if (seg != 0) {
        const float4 k0 = *(const float4*)(wsK + (size_t)16 * 512 + i * 32 + 8 * g);
        const float4 k1 = *(const float4*)(wsK + (size_t)16 * 512 + i * 32 + 8 * g + 4);
        const float4 n0 = *(const float4*)(wsN + (size_t)16 * 128 + i * 8);
        const float4 n1 = *(const float4*)(wsN + (size_t)16 * 128 + i * 8 + 4);
        kc[0]=k0.x; kc[1]=k0.y; kc[2]=k0.z; kc[3]=k0.w;
        kc[4]=k1.x; kc[5]=k1.y; kc[6]=k1.z; kc[7]=k1.w;
        nbc[0]=n0.x; nbc[1]=n0.y; nbc[2]=n0.z; nbc[3]=n0.w;
        nbc[4]=n1.x; nbc[5]=n1.y; nbc[6]=n1.z; nbc[7]=n1.w;
    }

    float w = 0.f;
#pragma unroll
    for (int j = 0; j < 16; ++j) {
        const int t = 16 * seg + j;
        float kr[8], nbr[8];
        if (seg == 0) {
            const float4 k0 = *(const float4*)(wsK + (size_t)j * 512 + i * 32 + 8 * g);
            const float4 k1 = *(const float4*)(wsK + (size_t)j * 512 + i * 32 + 8 * g + 4);
            const float4 n0 = *(const float4*)(wsN + (size_t)j * 128 + i * 8);
            const float4 n1 = *(const float4*)(wsN + (size_t)j * 128 + i * 8 + 4);
            kr[0]=k0.x; kr[1]=k0.y; kr[2]=k0.z; kr[3]=k0.w;
            kr[4]=k1.x; kr[5]=k1.y; kr[6]=k1.z; kr[7]=k1.w;
            nbr[0]=n0.x; nbr[1]=n0.y; nbr[2]=n0.z; nbr[3]=n0.w;
            nbr[4]=n1.x; nbr[5]=n1.y; nbr[6]=n1.z; nbr[7]=n1.w;
        } else {
#pragma unroll
            for (int k = 0; k < 8; ++k) { kr[k] = kc[k]; nbr[k] = nbc[k]; }
        }
        const float a0 = a[(size_t)b * (TT * 32) + t * 32 + (lane & 31)];
        const float u0 = u[(size_t)b * (TT * 8) + t * 8 + (lane & 7)];
        float gvp = kr[0] * __shfl(a0, 8*g+0) + kr[1] * __shfl(a0, 8*g+1)
                  + kr[2] * __shfl(a0, 8*g+2) + kr[3] * __shfl(a0, 8*g+3)
                  + kr[4] * __shfl(a0, 8*g+4) + kr[5] * __shfl(a0, 8*g+5)
                  + kr[6] * __shfl(a0, 8*g+6) + kr[7] * __shfl(a0, 8*g+7);
        float nbs = nbr[0] * __shfl(u0,0) + nbr[1] * __shfl(u0,1)
                  + nbr[2] * __shfl(u0,2) + nbr[3] * __shfl(u0,3)
                  + nbr[4] * __shfl(u0,4) + nbr[5] * __shfl(u0,5)
                  + nbr[6] * __shfl(u0,6) + nbr[7] * __shfl(u0,7);
        gvp += (g == 3) ? nbs : 0.f;
        gvp += __shfl_xor(gvp, 16);
        gvp += __shfl_xor(gvp, 32);
        float part = mcs[j][0] * __shfl(w, 4*g+0) + mcs[j][1] * __shfl(w, 4*g+1)
                   + mcs[j][2] * __shfl(w, 4*g+2) + mcs[j][3] * __shfl(w, 4*g+3);
        part += __shfl_xor(part, 16);
        part += __shfl_xor(part, 32);
        w = part + gvp;
    }
    if (lane < 16) wseg[(size_t)seg * 4096 + b * 16 + i] = w;

    if (blockIdx.x == 0) {
        float pr[4];
#pragma unroll
        for (int k = 0; k < 4; ++k) pr[k] = (4 * g + k == i) ? 1.f : 0.f;
#pragma unroll
        for (int j = 0; j < 16; ++j) {
            float np[4] = {0.f, 0.f, 0.f, 0.f};
#pragma unroll
            for (int q = 0; q < 16; ++q) {
                const float mq = __shfl(mcs[j][q & 3], i + 16 * (q >> 2));
#pragma unroll
                for (int k = 0; k < 4; ++k) np[k] += mq * __shfl(pr[k], q + 16 * g);
            }
#pragma unroll
            for (int k = 0; k < 4; ++k) pr[k] = np[k];
        }
#pragma unroll
        for (int k = 0; k < 4; ++k) wsp[i * 16 + 4 * g + k] = pr[k];
    }
    if (blockIdx.x == 256) {
        float pr[4];
#pragma unroll
        for (int k = 0; k < 4; ++k) pr[k] = mcs[0][k];
#pragma unroll
        for (int r = 0; r < 4; ++r) {
            float np[4] = {0.f, 0.f, 0.f, 0.f};
#pragma unroll
            for (int q = 0; q < 16; ++q) {
                const float sq = __shfl(pr[q & 3], i + 16 * (q >> 2));
#pragma unroll
                for (int k = 0; k < 4; ++k) np[k] += sq * __shfl(pr[k], q + 16 * g);
            }
#pragma unroll
            for (int k = 0; k < 4; ++k) pr[k] = np[k];
        }
#pragma unroll
        for (int k = 0; k < 4; ++k) wsp[256 + i * 16 + 4 * g + k] = pr[k];
    }
}

// ---------------------------------------------------------------------------
// Phase C (verified R10-R12, original form) — fallback pair of phAo_k.
// ---------------------------------------------------------------------------
__global__ __launch_bounds__(64) void phCo_k(
    const float* __restrict__ u, const float* __restrict__ a,
    const float* __restrict__ wsK, const float* __restrict__ wsM,
    const float* __restrict__ wsN, const float* __restrict__ bnd,
    float* __restrict__ out)
{
    const int lane = threadIdx.x;
    const int i = lane & 15, g = lane >> 4;
    const int seg = blockIdx.x >> 8;
    const int b = blockIdx.x & 255;

    float mcs[16][4];
#pragma unroll
    for (int j = 0; j < 16; ++j) {
        const int tc = (seg == 0) ? j : 16;
        const float4 v = *(const float4*)(wsM + (size_t)tc * 256 + i * 16 + 4 * g);
        mcs[j][0] = v.x; mcs[j][1] = v.y; mcs[j][2] = v.z; mcs[j][3] = v.w;
    }
    float kc[8], nbc[8];
    if (seg != 0) {
        const float4 k0 = *(const float4*)(wsK + (size_t)16 * 512 + i * 32 + 8 * g);
        const float4 k1 = *(const float4*)(wsK + (size_t)16 * 512 + i * 32 + 8 * g + 4);
        const float4 n0 = *(const float4*)(wsN + (size_t)16 * 128 + i * 8);
        const float4 n1 = *(const float4*)(wsN + (size_t)16 * 128 + i * 8 + 4);
        kc[0]=k0.x; kc[1]=k0.y; kc[2]=k0.z; kc[3]=k0.w;
        kc[4]=k1.x; kc[5]=k1.y; kc[6]=k1.z; kc[7]=k1.w;
        nbc[0]=n0.x; nbc[1]=n0.y; nbc[2]=n0.z; nbc[3]=n0.w;
        nbc[4]=n1.x; nbc[5]=n1.y; nbc[6]=n1.z; nbc[7]=n1.w;
    }

    float mn = bnd[(size_t)seg * 4096 + b * 16 + i];
    float* ob = out + (size_t)b * 4096 + (size_t)(16 * seg) * 16;
#pragma unroll
    for (int j = 0; j < 16; ++j) {
        const int t = 16 * seg + j;
        float kr[8], nbr[8];
        if (seg == 0) {
            const float4 k0 = *(const float4*)(wsK + (size_t)j * 512 + i * 32 + 8 * g);
            const float4 k1 = *(const float4*)(wsK + (size_t)j * 512 + i * 32 + 8 * g + 4);
            const float4 n0 = *(const float4*)(wsN + (size_t)j * 128 + i * 8);
            const float4 n1 = *(const float4*)(wsN + (size_t)j * 128 + i * 8 + 4);
            kr[0]=k0.x; kr[1]=k0.y; kr[2]=k0.z; kr[3]=k0.w;
            kr[4]=k1.x; kr[5]=k1.y; kr[6]=k1.z; kr[7]=k1.w;
            nbr[0]=n0.x; nbr[1]=n0.y; nbr[2]=n0.z; nbr[3]=n0.w;
            nbr[4]=n1.x; nbr[5]=n1.y; nbr[6]=n1.z; nbr[7]=n1.w;
        } else {
#pragma unroll
            for (int k = 0; k < 8; ++k) { kr[k] = kc[k]; nbr[k] = nbc[k]; }
        }
        const float a0 = a[(size_t)b * (TT * 32) + t * 32 + (lane & 31)];
        const float u0 = u[(size_t)b * (TT * 8) + t * 8 + (lane & 7)];
        float gvp = kr[0] * __shfl(a0, 8*g+0) + kr[1] * __shfl(a0, 8*g+1)
                  + kr[2] * __shfl(a0, 8*g+2) + kr[3] * __shfl(a0, 8*g+3)
                  + kr[4] * __shfl(a0, 8*g+4) + kr[5] * __shfl(a0, 8*g+5)
                  + kr[6] * __shfl(a0, 8*g+6) + kr[7] * __shfl(a0, 8*g+7);
        float nbs = nbr[0] * __shfl(u0,0) + nbr[1] * __shfl(u0,1)
                  + nbr[2] * __shfl(u0,2) + nbr[3] * __shfl(u0,3)
                  + nbr[4] * __shfl(u0,4) + nbr[5] * __shfl(u0,5)
                  + nbr[6] * __shfl(u0,6) + nbr[7] * __shfl(u0,7);
        gvp += (g == 3) ? nbs : 0.f;
        gvp += __shfl_xor(gvp, 16);
        gvp += __shfl_xor(gvp, 32);
        float part = mcs[j][0] * __shfl(mn, 4*g+0) + mcs[j][1] * __shfl(mn, 4*g+1)
                   + mcs[j][2] * __shfl(mn, 4*g+2) + mcs[j][3] * __shfl(mn, 4*g+3);
        part += __shfl_xor(part, 16);
        part += __shfl_xor(part, 32);
        mn = part + gvp;
        if (lane < 16) ob[j * 16 + i] = mn;
    }
}

// ---------------------------------------------------------------------------
// Fallback (verified R6/R8/R9, unchanged): serial mean pass if ws too small.
// ---------------------------------------------------------------------------
__global__ __launch_bounds__(64) void meanf_k(
    const float* __restrict__ mean0, const float* __restrict__ u,
    const float* __restrict__ a, const float* __restrict__ wsK,
    const float* __restrict__ wsM, const float* __restrict__ wsN,
    float* __restrict__ out)
{
    const int lane = threadIdx.x;
    const int b = blockIdx.x;
    const int i = lane & 15;
    const int g = lane >> 4;

    const float* ub = u + (size_t)b * TT * 8;
    const float* ab = a + (size_t)b * TT * 32;
    float* ob = out + (size_t)b * TT * 16;

    float mn = mean0[b * 16 + i];
    float Mc[16];
    {
        const float4* p = (const float4*)(wsM + i * 16);
        float4 x0 = p[0], x1 = p[1], x2 = p[2], x3 = p[3];
        Mc[0]=x0.x; Mc[1]=x0.y; Mc[2]=x0.z; Mc[3]=x0.w;
        Mc[4]=x1.x; Mc[5]=x1.y; Mc[6]=x1.z; Mc[7]=x1.w;
        Mc[8]=x2.x; Mc[9]=x2.y; Mc[10]=x2.z; Mc[11]=x2.w;
        Mc[12]=x3.x; Mc[13]=x3.y; Mc[14]=x3.z; Mc[15]=x3.w;
    }
    float gv;
    {
        float4 k0 = *(const float4*)(wsK + i * 32 + 8 * g);
        float4 k1 = *(const float4*)(wsK + i * 32 + 8 * g + 4);
        float4 n0 = *(const float4*)(wsN + i * 8);
        float4 n1 = *(const float4*)(wsN + i * 8 + 4);
        float u0 = ub[lane & 7];
        float a0 = ab[lane & 31];
        float part = k0.x * __shfl(a0, 8*g+0) + k0.y * __shfl(a0, 8*g+1)
                   + k0.z * __shfl(a0, 8*g+2) + k0.w * __shfl(a0, 8*g+3)
                   + k1.x * __shfl(a0, 8*g+4) + k1.y * __shfl(a0, 8*g+5)
                   + k1.z * __shfl(a0, 8*g+6) + k1.w * __shfl(a0, 8*g+7);
        float nbs = n0.x * __shfl(u0,0) + n0.y * __shfl(u0,1)
                  + n0.z * __shfl(u0,2) + n0.w * __shfl(u0,3)
                  + n1.x * __shfl(u0,4) + n1.y * __shfl(u0,5)
                  + n1.z * __shfl(u0,6) + n1.w * __shfl(u0,7);
        part += (g == 3) ? nbs : 0.f;
        part += __shfl_xor(part, 16);
        part += __shfl_xor(part, 32);
        gv = part;
    }
    float4 mA, mB, mC, mD, kp0, kp1, np0, np1;
    float upn, apn;
    {
        const float4* p = (const float4*)(wsM + 256 + i * 16);
        mA = p[0]; mB = p[1]; mC = p[2]; mD = p[3];
        kp0 = *(const float4*)(wsK + 512 + i * 32 + 8 * g);
        kp1 = *(const float4*)(wsK + 512 + i * 32 + 8 * g + 4);
        np0 = *(const float4*)(wsN + 128 + i * 8);
        np1 = *(const float4*)(wsN + 128 + i * 8 + 4);
        upn = ub[8 + (lane & 7)];
        apn = ab[32 + (lane & 31)];
    }

    for (int t = 0; t < TT; ++t) {
        const int t2 = (t + 2 < TT) ? t + 2 : TT - 1;
        const int s2 = (t2 < WARM) ? t2 : WARM;
        const float4* mp = (const float4*)(wsM + (size_t)s2 * 256 + i * 16);
        float4 l0 = mp[0], l1 = mp[1], l2 = mp[2], l3 = mp[3];
        float4 kl0 = *(const float4*)(wsK + (size_t)s2 * 512 + i * 32 + 8 * g);
        float4 kl1 = *(const float4*)(wsK + (size_t)s2 * 512 + i * 32 + 8 * g + 4);
        float4 nl0 = *(const float4*)(wsN + (size_t)s2 * 128 + i * 8);
        float4 nl1 = *(const float4*)(wsN + (size_t)s2 * 128 + i * 8 + 4);
        float ul = ub[t2 * 8 + (lane & 7)];
        float al = ab[t2 * 32 + (lane & 31)];

        float s0 = gv, s1 = 0.f, s2f = 0.f, s3 = 0.f;
#pragma unroll
        for (int q = 0; q < 16; q += 4) {
            s0  += Mc[q]     * __shfl(mn, q);
            s1  += Mc[q + 1] * __shfl(mn, q + 1);
            s2f += Mc[q + 2] * __shfl(mn, q + 2);
            s3  += Mc[q + 3] * __shfl(mn, q + 3);
        }
        mn = (s0 + s1) + (s2f + s3);
        if (lane < 16) ob[t * 16 + lane] = mn;

        float part = kp0.x * __shfl(apn, 8*g+0) + kp0.y * __shfl(apn, 8*g+1)
                   + kp0.z * __shfl(apn, 8*g+2) + kp0.w * __shfl(apn, 8*g+3)
                   + kp1.x * __shfl(apn, 8*g+4) + kp1.y * __shfl(apn, 8*g+5)
                   + kp1.z * __shfl(apn, 8*g+6) + kp1.w * __shfl(apn, 8*g+7);
        float nbs = np0.x * __shfl(upn,0) + np0.y * __shfl(upn,1)
                  + np0.z * __shfl(upn,2) + np0.w * __shfl(upn,3)
                  + np1.x * __shfl(upn,4) + np1.y * __shfl(upn,5)
                  + np1.z * __shfl(upn,6) + np1.w * __shfl(upn,7);
        part += (g == 3) ? nbs : 0.f;
        part += __shfl_xor(part, 16);
        part += __shfl_xor(part, 32);
        gv = part;

        Mc[0]=mA.x; Mc[1]=mA.y; Mc[2]=mA.z; Mc[3]=mA.w;
        Mc[4]=mB.x; Mc[5]=mB.y; Mc[6]=mB.z; Mc[7]=mB.w;
        Mc[8]=mC.x; Mc[9]=mC.y; Mc[10]=mC.z; Mc[11]=mC.w;
        Mc[12]=mD.x; Mc[13]=mD.y; Mc[14]=mD.z; Mc[15]=mD.w;
        mA = l0; mB = l1; mC = l2; mD = l3;
        kp0 = kl0; kp1 = kl1; np0 = nl0; np1 = nl1;
        upn = ul; apn = al;
    }
}

extern "C" void kernel_launch(void* const* d_in, const int* in_sizes, int n_in,
                              void* d_out, int out_size, void* d_ws, size_t ws_size,
                              hipStream_t stream) {
    const float* mean0 = nullptr; const float* cov0 = nullptr;
    const float* u = nullptr;     const float* a = nullptr;
    const float* Mm = nullptr;    const float* Nm = nullptr;
    const float* dv = nullptr;    const float* Bm = nullptr;
    const float* Cm = nullptr;    const float* nxp = nullptr;
    const float* nap = nullptr;
    for (int i = 0; i < n_in; ++i) {
        const float* p = (const float*)d_in[i];
        switch (in_sizes[i]) {
            case 256 * 16:        mean0 = p; break;
            case 256 * 256:       cov0 = p; break;
            case 256 * 256 * 8:   u = p; break;
            case 256 * 256 * 32:  a = p; break;
            case 256:             if (!Mm) Mm = p; else Nm = p; break;
            case 16:              if (!dv) dv = p; else nxp = p; break;
            case 128:             Bm = p; break;
            case 512:             Cm = p; break;
            case 32:              nap = p; break;
            default: break;
        }
    }
    float* ws   = (float*)d_ws;
    float* wsK  = ws + OFF_K;
    float* wsM  = ws + OFF_MC;
    float* wsN  = ws + OFF_NB;
    float* wsp  = ws + OFF_P0;
    float* wseg = ws + OFF_WSEG;
    float* bnd  = ws + OFF_BND;
    float* gv   = ws + OFF_GV;

    chain_k<<<WARM + 1, 64, 0, stream>>>(Mm, Nm, dv, Bm, Cm, nxp, nap, cov0,
                                         wsK, wsM, wsN);
    if (ws_size >= NEED_WS2_BYTES) {
        phA_k<<<16 * 256, 64, 0, stream>>>(u, a, wsK, wsM, wsN, wseg, wsp, gv);
        phB_k<<<256, 64, 0, stream>>>(mean0, wsp, wseg, bnd);
        phC_k<<<16 * 256, 64, 0, stream>>>(wsM, gv, bnd, (float*)d_out);
    } else if (ws_size >= NEED_WS_BYTES) {
        phAo_k<<<16 * 256, 64, 0, stream>>>(u, a, wsK, wsM, wsN, wseg, wsp);
        phB_k<<<256, 64, 0, stream>>>(mean0, wsp, wseg, bnd);
        phCo_k<<<16 * 256, 64, 0, stream>>>(u, a, wsK, wsM, wsN, bnd, (float*)d_out);
    } else {
        meanf_k<<<256, 64, 0, stream>>>(mean0, u, a, wsK, wsM, wsN, (float*)d_out);
    }
}

// Round 4
// 152.593 us; speedup vs baseline: 1.4350x; 1.0753x over previous
//
#include <hip/hip_runtime.h>
#include <math.h>

#define TT 256
#define WARM 16
// ws float offsets (chain outputs + scan intermediates only)
#define OFF_K    5632   // 17 x 512 -> 14336
#define OFF_MC   14336  // 17 x 256 -> 18688
#define OFF_NB   18688  // 17 x 128 -> 20864
#define OFF_P0   20864  // Mseg0 (256) -> 21120
#define OFF_PP   21120  // Mc16^16 (256) -> 21376
#define OFF_WSEG 21376  // 16 x 256 x 16 -> 86912
#define OFF_BND  86912  // 16 x 256 x 16 -> 152448
#define OFF_GV   152448 // 256 x 256 x 16 -> 1201024 (R17: holds w-partials)
#define OFF_PFX0 1201024 // 16 x 256 -> 1205120 (seg0 prefix products)
#define OFF_PFX1 1205120 // 16 x 256 -> 1209216 (Mc16 powers 1..16)
#define NEED_WS_BYTES ((size_t)152448 * 4)
#define NEED_WS3_BYTES ((size_t)1209216 * 4)

__device__ __forceinline__ float softplus(float v) {
    return fmaxf(v, 0.0f) + log1pf(expf(-fabsf(v)));
}

// Shuffle-based Gauss-Jordan, [X|I] -> [I|X^-1] (verified R5-R12).
// Layout: lane (i, gq) holds aug[i][8*gq+k], k=0..7.
// R17: back to FULLY UNROLLED (R15 form) — R16's rolled form regressed
// chain_k 45.7->53.0 us (runtime lane-index math + lost cross-iteration
// scheduling outweigh any I-footprint savings).
__device__ __forceinline__ void gj16(float (&aug)[8], const int i, const int gq) {
#pragma unroll
    for (int j = 0; j < 16; ++j) {
        float prow[8];
#pragma unroll
        for (int k = 0; k < 8; ++k) prow[k] = __shfl(aug[k], j + 16 * gq);
        const float pjj = __shfl(aug[j & 7], j + 16 * (j >> 3));
        const float cij = __shfl(aug[j & 7], i + 16 * (j >> 3));
        const float pivinv = 1.0f / pjj;
        const float f = cij * pivinv;
#pragma unroll
        for (int k = 0; k < 8; ++k)
            aug[k] = (i == j) ? prow[k] * pivinv : aug[k] - f * prow[k];
    }
}

// Load a full 16-float row from a stride-20 LDS matrix into registers (4x b128).
#define LD_ROW16(Mt, r, row) do { \
    const float4 r0_ = *(const float4*)&Mt[r][0]; \
    const float4 r1_ = *(const float4*)&Mt[r][4]; \
    const float4 r2_ = *(const float4*)&Mt[r][8]; \
    const float4 r3_ = *(const float4*)&Mt[r][12]; \
    row[0]=r0_.x;  row[1]=r0_.y;  row[2]=r0_.z;  row[3]=r0_.w; \
    row[4]=r1_.x;  row[5]=r1_.y;  row[6]=r1_.z;  row[7]=r1_.w; \
    row[8]=r2_.x;  row[9]=r2_.y;  row[10]=r2_.z; row[11]=r2_.w; \
    row[12]=r3_.x; row[13]=r3_.y; row[14]=r3_.z; row[15]=r3_.w; } while (0)

// ---------------------------------------------------------------------------
// Fused chain kernel (R13 math, R15 data path — verified).
// ---------------------------------------------------------------------------
__global__ __launch_bounds__(64) void chain_k(
    const float* __restrict__ Mm, const float* __restrict__ Nm,
    const float* __restrict__ dvec, const float* __restrict__ Bm,
    const float* __restrict__ Cm, const float* __restrict__ nx,
    const float* __restrict__ na, const float* __restrict__ cov0,
    float* __restrict__ wsK, float* __restrict__ wsM, float* __restrict__ wsN)
{
    __shared__ float qm[16][17], qn[16][17], T0s[16][17];
    __shared__ float sC[32][17], sW[16][33], sAm[16][17], sBm[16][9];
    __shared__ float sCA[32][17], sCB[32][9], sP[16][17], sK[16][33];
    __shared__ float spv[16], d2[16], sNai[32], sNxi[16];
    // stride-20 matmul arenas: rows are 80B apart -> float4-aligned, and
    // column accesses hit <=2-way bank aliasing (free).
    __shared__ __attribute__((aligned(16))) float mE[16][20];
    __shared__ __attribute__((aligned(16))) float mET[16][20];
    __shared__ __attribute__((aligned(16))) float mF[16][20];
    __shared__ __attribute__((aligned(16))) float mH[16][20];
    __shared__ __attribute__((aligned(16))) float mZ[16][20];
    __shared__ __attribute__((aligned(16))) float mT[16][20];
    __shared__ __attribute__((aligned(16))) float mT2[16][20];
    __shared__ __attribute__((aligned(16))) float mL[16][20];
    const int lane = threadIdx.x;
    const int t = blockIdx.x;            // 0..16
    const int n = t + 1;                 // steps to apply
    const int i = lane & 15, gq = lane >> 4;
    const int jj = gq << 2;              // 4-wide column chunk this lane owns

    // ---- load inputs ----
    for (int e = lane; e < 256; e += 64) { qm[e >> 4][e & 15] = Mm[e]; qn[e >> 4][e & 15] = Nm[e]; }
    for (int e = lane; e < 512; e += 64) sC[e >> 4][e & 15] = Cm[e];
    for (int e = lane; e < 128; e += 64) sBm[e >> 3][e & 7] = Bm[e];
    if (lane < 16) {
        float s = softplus(dvec[lane]);
        spv[lane] = sqrtf(s);
        d2[lane] = 1.0f / sqrtf(1.0f + s);
        sNxi[lane] = 1.0f / (softplus(nx[lane]) + 1e-4f);
    }
    if (lane < 32) sNai[lane] = 1.0f / (softplus(na[lane]) + 1e-4f);
    __syncthreads();

    // ---- register MGS QR on both matrices (verified R12, rolled) ----
    {
        const int j0 = lane & 15;
        const int mi = lane >> 4;
        float (*Qs)[17] = (mi == 1) ? qn : qm;
        float col[16];
#pragma unroll
        for (int r = 0; r < 16; ++r) col[r] = Qs[r][j0];
        const int base = lane & 48;
#pragma unroll 1
        for (int j = 0; j < 16; ++j) {
            float qj[16];
#pragma unroll
            for (int r = 0; r < 16; ++r) qj[r] = __shfl(col[r], base + j);
            float nrm = 0.f;
#pragma unroll
            for (int r = 0; r < 16; ++r) nrm += qj[r] * qj[r];
            const float scal = 1.0f / sqrtf(nrm);
#pragma unroll
            for (int r = 0; r < 16; ++r) qj[r] *= scal;
            if (j0 == j) {
#pragma unroll
                for (int r = 0; r < 16; ++r) col[r] = qj[r];
            } else if (j0 > j) {
                float pr = 0.f;
#pragma unroll
                for (int r = 0; r < 16; ++r) pr += qj[r] * col[r];
#pragma unroll
                for (int r = 0; r < 16; ++r) col[r] -= pr * qj[r];
            }
        }
        __syncthreads();
        if (mi < 2) {
#pragma unroll
            for (int r = 0; r < 16; ++r) Qs[r][j0] = col[r];
        }
    }
    __syncthreads();

    // ---- assembly: A, W, base map E/F/H, CA, CB (verified patterns) ----
    for (int e = lane; e < 256; e += 64) {
        int ii = e >> 4, j = e & 15;
        float s = 0.f;
        for (int q = 0; q < 16; ++q) s += qm[ii][q] * d2[q] * qn[j][q];
        T0s[ii][j] = spv[ii] * s;
    }
    __syncthreads();
    for (int e = lane; e < 256; e += 64) {
        int ii = e >> 4, j = e & 15;
        float s = 0.f;
        for (int q = 0; q < 16; ++q) s += qn[ii][q] * T0s[q][j];
        sAm[ii][j] = s;
    }
    for (int e = lane; e < 512; e += 64) {
        int q = e >> 5, r = e & 31;
        sW[q][r] = sC[r][q] * sNai[r];
    }
    __syncthreads();
    for (int e = lane; e < 256; e += 64) {
        int ii = e >> 4, j = e & 15;
        float g = 0.f;
        for (int r = 0; r < 32; ++r) g += sC[r][ii] * sW[j][r];
        mF[ii][j] = g + ((ii == j) ? sNxi[ii] : 0.f);
        const float ev = sNxi[ii] * sAm[ii][j];
        mE[ii][j] = ev;
        mET[j][ii] = ev;
        float hsum = 0.f;
        for (int q = 0; q < 16; ++q) hsum += sAm[q][ii] * sNxi[q] * sAm[q][j];
        mH[ii][j] = hsum;
    }
    for (int e = lane; e < 512; e += 64) {
        int r = e >> 4, j = e & 15;
        float s = 0.f;
        for (int q = 0; q < 16; ++q) s += sC[r][q] * sAm[q][j];
        sCA[r][j] = s;
    }
    for (int e = lane; e < 256; e += 64) {
        int r = e >> 3, j = e & 7;
        float s = 0.f;
        for (int q = 0; q < 16; ++q) s += sC[r][q] * sBm[q][j];
        sCB[r][j] = s;
    }
    __syncthreads();

    // ---- E rows register-resident across the m-loop (R13-style residency) ----
    float Er[16], ETr[16];
    LD_ROW16(mE, i, Er);
    LD_ROW16(mET, i, ETr);

    // ---- L0 = inv(cov0) -> mL ----
    float aug[8];
#pragma unroll
    for (int k = 0; k < 8; ++k)
        aug[k] = (gq < 2) ? cov0[i * 16 + 8 * gq + k]
                          : ((8 * (gq - 2) + k == i) ? 1.f : 0.f);
    gj16(aug, i, gq);
    if (gq >= 2) {
        *(float4*)&mL[i][8 * (gq - 2)]     = make_float4(aug[0], aug[1], aug[2], aug[3]);
        *(float4*)&mL[i][8 * (gq - 2) + 4] = make_float4(aug[4], aug[5], aug[6], aug[7]);
    }
    __syncthreads();

    // ---- interleaved LSB-first double-and-apply (batched-LDS matmuls) ----
#pragma unroll 1
    for (int m = 0; m < 5; ++m) {
        if ((n >> m) & 1) {
            // apply: L = F - E (L+H)^-1 E^T
            if (gq < 2) {
                const float4 l0 = *(const float4*)&mL[i][8 * gq];
                const float4 l1 = *(const float4*)&mL[i][8 * gq + 4];
                const float4 h0 = *(const float4*)&mH[i][8 * gq];
                const float4 h1 = *(const float4*)&mH[i][8 * gq + 4];
                aug[0] = l0.x + h0.x; aug[1] = l0.y + h0.y;
                aug[2] = l0.z + h0.z; aug[3] = l0.w + h0.w;
                aug[4] = l1.x + h1.x; aug[5] = l1.y + h1.y;
                aug[6] = l1.z + h1.z; aug[7] = l1.w + h1.w;
            } else {
#pragma unroll
                for (int k = 0; k < 8; ++k) aug[k] = (8 * (gq - 2) + k == i) ? 1.f : 0.f;
            }
            gj16(aug, i, gq);
            if (gq >= 2) {
                *(float4*)&mZ[i][8 * (gq - 2)]     = make_float4(aug[0], aug[1], aug[2], aug[3]);
                *(float4*)&mZ[i][8 * (gq - 2) + 4] = make_float4(aug[4], aug[5], aug[6], aug[7]);
            }
            __syncthreads();
            // T = E * Z : batch ALL column loads first, then FMA
            {
                float4 zz[16];
#pragma unroll
                for (int q = 0; q < 16; ++q) zz[q] = *(const float4*)&mZ[q][jj];
                float4 tacc = make_float4(0.f, 0.f, 0.f, 0.f);
#pragma unroll
                for (int q = 0; q < 16; ++q) {
                    tacc.x += Er[q] * zz[q].x; tacc.y += Er[q] * zz[q].y;
                    tacc.z += Er[q] * zz[q].z; tacc.w += Er[q] * zz[q].w;
                }
                *(float4*)&mT[i][jj] = tacc;
            }
            __syncthreads();
            // L' = F - T * E^T : batch T-row + all ET columns, then FMA
            {
                float Tr[16];
                LD_ROW16(mT, i, Tr);
                float4 et[16];
#pragma unroll
                for (int q = 0; q < 16; ++q) et[q] = *(const float4*)&mET[q][jj];
                float4 l = *(const float4*)&mF[i][jj];
#pragma unroll
                for (int q = 0; q < 16; ++q) {
                    l.x -= Tr[q] * et[q].x; l.y -= Tr[q] * et[q].y;
                    l.z -= Tr[q] * et[q].z; l.w -= Tr[q] * et[q].w;
                }
                __syncthreads();
                *(float4*)&mL[i][jj] = l;
            }
            __syncthreads();
        }
        if (m < 4 && (n >> (m + 1)) != 0) {
            // double: Z=(F+H)^-1, T=EZ, T2=E^T Z, F'=F-T E^T, H'=H-T2 E, E'=T E
            if (gq < 2) {
                const float4 f0 = *(const float4*)&mF[i][8 * gq];
                const float4 f1 = *(const float4*)&mF[i][8 * gq + 4];
                const float4 h0 = *(const float4*)&mH[i][8 * gq];
                const float4 h1 = *(const float4*)&mH[i][8 * gq + 4];
                aug[0] = f0.x + h0.x; aug[1] = f0.y + h0.y;
                aug[2] = f0.z + h0.z; aug[3] = f0.w + h0.w;
                aug[4] = f1.x + h1.x; aug[5] = f1.y + h1.y;
                aug[6] = f1.z + h1.z; aug[7] = f1.w + h1.w;
            } else {
#pragma unroll
                for (int k = 0; k < 8; ++k) aug[k] = (8 * (gq - 2) + k == i) ? 1.f : 0.f;
            }
            gj16(aug, i, gq);
            if (gq >= 2) {
                *(float4*)&mZ[i][8 * (gq - 2)]     = make_float4(aug[0], aug[1], aug[2], aug[3]);
                *(float4*)&mZ[i][8 * (gq - 2) + 4] = make_float4(aug[4], aug[5], aug[6], aug[7]);
            }
            __syncthreads();
            // T = E*Z, T2 = E^T*Z : batch Z columns once, share
            {
                float4 zz[16];
#pragma unroll
                for (int q = 0; q < 16; ++q) zz[q] = *(const float4*)&mZ[q][jj];
                float4 tacc = make_float4(0.f, 0.f, 0.f, 0.f);
                float4 t2acc = make_float4(0.f, 0.f, 0.f, 0.f);
#pragma unroll
                for (int q = 0; q < 16; ++q) {
                    tacc.x  += Er[q]  * zz[q].x; tacc.y  += Er[q]  * zz[q].y;
                    tacc.z  += Er[q]  * zz[q].z; tacc.w  += Er[q]  * zz[q].w;
                    t2acc.x += ETr[q] * zz[q].x; t2acc.y += ETr[q] * zz[q].y;
                    t2acc.z += ETr[q] * zz[q].z; t2acc.w += ETr[q] * zz[q].w;
                }
                *(float4*)&mT[i][jj]  = tacc;
                *(float4*)&mT2[i][jj] = t2acc;
            }
            __syncthreads();
            // F' = F - T*E^T ; H' = H - T2*E ; E' = T*E   (E cols in halves of 8)
            {
                float Tr[16], T2r[16];
                LD_ROW16(mT, i, Tr);
                LD_ROW16(mT2, i, T2r);
                float4 f  = *(const float4*)&mF[i][jj];
                float4 hh = *(const float4*)&mH[i][jj];
                float4 en = make_float4(0.f, 0.f, 0.f, 0.f);
#pragma unroll
                for (int qh = 0; qh < 16; qh += 8) {
                    float4 eq[8], etq[8];
#pragma unroll
                    for (int q0 = 0; q0 < 8; ++q0) {
                        eq[q0]  = *(const float4*)&mE[qh + q0][jj];
                        etq[q0] = *(const float4*)&mET[qh + q0][jj];
                    }
#pragma unroll
                    for (int q0 = 0; q0 < 8; ++q0) {
                        const float tq = Tr[qh + q0], t2q = T2r[qh + q0];
                        f.x  -= tq  * etq[q0].x; f.y  -= tq  * etq[q0].y;
                        f.z  -= tq  * etq[q0].z; f.w  -= tq  * etq[q0].w;
                        hh.x -= t2q * eq[q0].x;  hh.y -= t2q * eq[q0].y;
                        hh.z -= t2q * eq[q0].z;  hh.w -= t2q * eq[q0].w;
                        en.x += tq  * eq[q0].x;  en.y += tq  * eq[q0].y;
                        en.z += tq  * eq[q0].z;  en.w += tq  * eq[q0].w;
                    }
                }
                __syncthreads();   // all reads of E/ET/F/H done before overwrite
                *(float4*)&mF[i][jj] = f;
                *(float4*)&mH[i][jj] = hh;
                *(float4*)&mE[i][jj] = en;
                mET[jj + 0][i] = en.x; mET[jj + 1][i] = en.y;
                mET[jj + 2][i] = en.z; mET[jj + 3][i] = en.w;
            }
            __syncthreads();
            // refresh register-resident E rows after the E rewrite
            LD_ROW16(mE, i, Er);
            LD_ROW16(mET, i, ETr);
        }
    }

    // ---- epilogue (verified math): P = L^-1, K = P W, Mc = A - K CA, Nb = B - K CB
    if (gq < 2) {
        const float4 l0 = *(const float4*)&mL[i][8 * gq];
        const float4 l1 = *(const float4*)&mL[i][8 * gq + 4];
        aug[0] = l0.x; aug[1] = l0.y; aug[2] = l0.z; aug[3] = l0.w;
        aug[4] = l1.x; aug[5] = l1.y; aug[6] = l1.z; aug[7] = l1.w;
    } else {
#pragma unroll
        for (int k = 0; k < 8; ++k) aug[k] = (8 * (gq - 2) + k == i) ? 1.f : 0.f;
    }
    gj16(aug, i, gq);
    if (gq >= 2) {
#pragma unroll
        for (int k = 0; k < 8; ++k) sP[i][8 * (gq - 2) + k] = aug[k];
    }
    __syncthreads();
#pragma unroll
    for (int m = 0; m < 8; ++m) {
        const int e = lane + 64 * m, ii = e >> 5, rr = e & 31;
        float s = 0.f;
#pragma unroll
        for (int q = 0; q < 16; ++q) s += sP[ii][q] * sW[q][rr];
        sK[ii][rr] = s;
        wsK[(size_t)t * 512 + e] = s;
    }
    __syncthreads();
#pragma unroll
    for (int m = 0; m < 4; ++m) {
        const int e = lane + 64 * m, ii = e >> 4, jjm = e & 15;
        float s = sAm[ii][jjm];
#pragma unroll
        for (int r = 0; r < 32; ++r) s -= sK[ii][r] * sCA[r][jjm];
        wsM[(size_t)t * 256 + e] = s;
    }
#pragma unroll
    for (int m = 0; m < 2; ++m) {
        const int e = lane + 64 * m, ii = e >> 3, jjm = e & 7;
        float s = sBm[ii][jjm];
#pragma unroll
        for (int r = 0; r < 32; ++r) s -= sK[ii][r] * sCB[r][jjm];
        wsN[(size_t)t * 128 + e] = s;
    }
}

// ---------------------------------------------------------------------------
// Phase A v3 (R17): as R16 (direct a/u vector loads) but stores the RUNNING
// scan partial w_j (not raw gvp) into the gv buffer, so phC needs no serial
// replay: mn_j = P_j * bnd_seg + w_j. Blocks 0/256 additionally store all 16
// prefix matrices (seg0 prefixes / Mc16 powers) for phC.
// ---------------------------------------------------------------------------
__global__ __launch_bounds__(64) void phA_k(
    const float* __restrict__ u, const float* __restrict__ a,
    const float* __restrict__ wsK, const float* __restrict__ wsM,
    const float* __restrict__ wsN, float* __restrict__ wseg,
    float* __restrict__ wsp, float* __restrict__ gv,
    float* __restrict__ pfx0, float* __restrict__ pfx1)
{
    const int lane = threadIdx.x;
    const int i = lane & 15, g = lane >> 4;
    const int seg = blockIdx.x >> 8;
    const int b = blockIdx.x & 255;

    float mcs[16][4];
#pragma unroll
    for (int j = 0; j < 16; ++j) {
        const int tc = (seg == 0) ? j : 16;
        const float4 v = *(const float4*)(wsM + (size_t)tc * 256 + i * 16 + 4 * g);
        mcs[j][0] = v.x; mcs[j][1] = v.y; mcs[j][2] = v.z; mcs[j][3] = v.w;
    }
    float kc[8], nbc[8];
    if (seg != 0) {
        const float4 k0 = *(const float4*)(wsK + (size_t)16 * 512 + i * 32 + 8 * g);
        const float4 k1 = *(const float4*)(wsK + (size_t)16 * 512 + i * 32 + 8 * g + 4);
        const float4 n0 = *(const float4*)(wsN + (size_t)16 * 128 + i * 8);
        const float4 n1 = *(const float4*)(wsN + (size_t)16 * 128 + i * 8 + 4);
        kc[0]=k0.x; kc[1]=k0.y; kc[2]=k0.z; kc[3]=k0.w;
        kc[4]=k1.x; kc[5]=k1.y; kc[6]=k1.z; kc[7]=k1.w;
        nbc[0]=n0.x; nbc[1]=n0.y; nbc[2]=n0.z; nbc[3]=n0.w;
        nbc[4]=n1.x; nbc[5]=n1.y; nbc[6]=n1.z; nbc[7]=n1.w;
    }

    float w = 0.f;
#pragma unroll
    for (int j = 0; j < 16; ++j) {
        const int t = 16 * seg + j;
        float kr[8], nbr[8];
        if (seg == 0) {
            const float4 k0 = *(const float4*)(wsK + (size_t)j * 512 + i * 32 + 8 * g);
            const float4 k1 = *(const float4*)(wsK + (size_t)j * 512 + i * 32 + 8 * g + 4);
            const float4 n0 = *(const float4*)(wsN + (size_t)j * 128 + i * 8);
            const float4 n1 = *(const float4*)(wsN + (size_t)j * 128 + i * 8 + 4);
            kr[0]=k0.x; kr[1]=k0.y; kr[2]=k0.z; kr[3]=k0.w;
            kr[4]=k1.x; kr[5]=k1.y; kr[6]=k1.z; kr[7]=k1.w;
            nbr[0]=n0.x; nbr[1]=n0.y; nbr[2]=n0.z; nbr[3]=n0.w;
            nbr[4]=n1.x; nbr[5]=n1.y; nbr[6]=n1.z; nbr[7]=n1.w;
        } else {
#pragma unroll
            for (int k = 0; k < 8; ++k) { kr[k] = kc[k]; nbr[k] = nbc[k]; }
        }
        // direct vector loads: lane (i,g) needs a[b][t][8g..8g+7], u[b][t][0..7]
        const float4 av0 = *(const float4*)(a + (size_t)b * (TT * 32) + t * 32 + 8 * g);
        const float4 av1 = *(const float4*)(a + (size_t)b * (TT * 32) + t * 32 + 8 * g + 4);
        const float4 uv0 = *(const float4*)(u + (size_t)b * (TT * 8) + t * 8);
        const float4 uv1 = *(const float4*)(u + (size_t)b * (TT * 8) + t * 8 + 4);
        float gvp = kr[0] * av0.x + kr[1] * av0.y + kr[2] * av0.z + kr[3] * av0.w
                  + kr[4] * av1.x + kr[5] * av1.y + kr[6] * av1.z + kr[7] * av1.w;
        float nbs = nbr[0] * uv0.x + nbr[1] * uv0.y + nbr[2] * uv0.z + nbr[3] * uv0.w
                  + nbr[4] * uv1.x + nbr[5] * uv1.y + nbr[6] * uv1.z + nbr[7] * uv1.w;
        gvp += (g == 3) ? nbs : 0.f;
        gvp += __shfl_xor(gvp, 16);
        gvp += __shfl_xor(gvp, 32);
        float part = mcs[j][0] * __shfl(w, 4*g+0) + mcs[j][1] * __shfl(w, 4*g+1)
                   + mcs[j][2] * __shfl(w, 4*g+2) + mcs[j][3] * __shfl(w, 4*g+3);
        part += __shfl_xor(part, 16);
        part += __shfl_xor(part, 32);
        w = part + gvp;
        if (lane < 16) gv[(size_t)t * 4096 + b * 16 + i] = w;   // running partial
    }
    if (lane < 16) wseg[(size_t)seg * 4096 + b * 16 + i] = w;

    if (blockIdx.x == 0) {          // prefixes P0j = Mc_j ... Mc_0 (store all)
        float pr[4];
#pragma unroll
        for (int k = 0; k < 4; ++k) pr[k] = (4 * g + k == i) ? 1.f : 0.f;
#pragma unroll
        for (int j = 0; j < 16; ++j) {
            float np[4] = {0.f, 0.f, 0.f, 0.f};
#pragma unroll
            for (int q = 0; q < 16; ++q) {
                const float mq = __shfl(mcs[j][q & 3], i + 16 * (q >> 2));
#pragma unroll
                for (int k = 0; k < 4; ++k) np[k] += mq * __shfl(pr[k], q + 16 * g);
            }
#pragma unroll
            for (int k = 0; k < 4; ++k) pr[k] = np[k];
#pragma unroll
            for (int k = 0; k < 4; ++k) pfx0[j * 256 + i * 16 + 4 * g + k] = pr[k];
        }
#pragma unroll
        for (int k = 0; k < 4; ++k) wsp[i * 16 + 4 * g + k] = pr[k];
    }
    if (blockIdx.x == 256) {        // powers Mc16^(r+1), r=0..15 (store all)
        float pr[4];
#pragma unroll
        for (int k = 0; k < 4; ++k) pr[k] = mcs[0][k];
#pragma unroll
        for (int k = 0; k < 4; ++k) pfx1[i * 16 + 4 * g + k] = pr[k];
#pragma unroll 1
        for (int r = 1; r < 16; ++r) {
            float np[4] = {0.f, 0.f, 0.f, 0.f};
#pragma unroll
            for (int q = 0; q < 16; ++q) {
                const float mq = __shfl(mcs[0][q & 3], i + 16 * (q >> 2));
#pragma unroll
                for (int k = 0; k < 4; ++k) np[k] += mq * __shfl(pr[k], q + 16 * g);
            }
#pragma unroll
            for (int k = 0; k < 4; ++k) pr[k] = np[k];
#pragma unroll
            for (int k = 0; k < 4; ++k) pfx1[r * 256 + i * 16 + 4 * g + k] = pr[k];
        }
#pragma unroll
        for (int k = 0; k < 4; ++k) wsp[256 + i * 16 + 4 * g + k] = pr[k];  // Mc16^16
    }
}

// ---------------------------------------------------------------------------
// Phase B (verified R9-R12, unchanged).
// ---------------------------------------------------------------------------
__global__ __launch_bounds__(64) void phB_k(
    const float* __restrict__ mean0, const float* __restrict__ wsp,
    const float* __restrict__ wseg, float* __restrict__ bnd)
{
    const int lane = threadIdx.x;
    const int i = lane & 15, g = lane >> 4;
    const int b = blockIdx.x;

    const float4 v0 = *(const float4*)(wsp + i * 16 + 4 * g);
    const float4 vp = *(const float4*)(wsp + 256 + i * 16 + 4 * g);
    const float m0s[4] = {v0.x, v0.y, v0.z, v0.w};
    const float mps[4] = {vp.x, vp.y, vp.z, vp.w};
    float wv[16];
#pragma unroll
    for (int s = 0; s < 16; ++s) wv[s] = wseg[(size_t)s * 4096 + b * 16 + i];

    float mn = mean0[b * 16 + i];
#pragma unroll
    for (int s = 0; s < 16; ++s) {
        if (lane < 16) bnd[(size_t)s * 4096 + b * 16 + i] = mn;
        const float c0 = (s == 0) ? m0s[0] : mps[0];
        const float c1 = (s == 0) ? m0s[1] : mps[1];
        const float c2 = (s == 0) ? m0s[2] : mps[2];
        const float c3 = (s == 0) ? m0s[3] : mps[3];
        float part = c0 * __shfl(mn, 4 * g + 0) + c1 * __shfl(mn, 4 * g + 1)
                   + c2 * __shfl(mn, 4 * g + 2) + c3 * __shfl(mn, 4 * g + 3);
        part += __shfl_xor(part, 16);
        part += __shfl_xor(part, 32);
        mn = part + wv[s];
    }
}

// ---------------------------------------------------------------------------
// Phase C v3 (R17): fully parallel — zero shuffles, zero serial chain.
// out[b][16s+j] = P_j * bnd[s][b] + w_j[b].  Lane (i,g) handles rows i of
// steps j = 4g+k, k=0..3: 16-FMA dot with the b-independent prefix matrix.
// ---------------------------------------------------------------------------
__global__ __launch_bounds__(64) void phC_k(
    const float* __restrict__ pfx0, const float* __restrict__ pfx1,
    const float* __restrict__ wpart, const float* __restrict__ bnd,
    float* __restrict__ out)
{
    const int lane = threadIdx.x;
    const int i = lane & 15, g = lane >> 4;
    const int seg = blockIdx.x >> 8;
    const int b = blockIdx.x & 255;

    const float* bp = bnd + (size_t)seg * 4096 + b * 16;
    const float4 bv0 = *(const float4*)(bp);
    const float4 bv1 = *(const float4*)(bp + 4);
    const float4 bv2 = *(const float4*)(bp + 8);
    const float4 bv3 = *(const float4*)(bp + 12);
    const float* P = (seg == 0) ? pfx0 : pfx1;
    float* ob = out + (size_t)b * 4096 + (size_t)(16 * seg) * 16;
#pragma unroll
    for (int k = 0; k < 4; ++k) {
        const int j = 4 * g + k;
        const float* pr = P + (size_t)j * 256 + i * 16;
        const float4 p0 = *(const float4*)(pr);
        const float4 p1 = *(const float4*)(pr + 4);
        const float4 p2 = *(const float4*)(pr + 8);
        const float4 p3 = *(const float4*)(pr + 12);
        float s = p0.x * bv0.x + p0.y * bv0.y + p0.z * bv0.z + p0.w * bv0.w
                + p1.x * bv1.x + p1.y * bv1.y + p1.z * bv1.z + p1.w * bv1.w
                + p2.x * bv2.x + p2.y * bv2.y + p2.z * bv2.z + p2.w * bv2.w
                + p3.x * bv3.x + p3.y * bv3.y + p3.z * bv3.z + p3.w * bv3.w;
        s += wpart[(size_t)(16 * seg + j) * 4096 + b * 16 + i];
        ob[j * 16 + i] = s;
    }
}

// ---------------------------------------------------------------------------
// Phase A (verified R10-R12, original form) — fallback when ws fits the old
// layout but not the gv/pfx buffers.
// ---------------------------------------------------------------------------
__global__ __launch_bounds__(64) void phAo_k(
    const float* __restrict__ u, const float* __restrict__ a,
    const float* __restrict__ wsK, const float* __restrict__ wsM,
    const float* __restrict__ wsN, float* __restrict__ wseg,
    float* __restrict__ wsp)
{
    const int lane = threadIdx.x;
    const int i = lane & 15, g = lane >> 4;
    const int seg = blockIdx.x >> 8;
    const int b = blockIdx.x & 255;

    float mcs[16][4];
#pragma unroll
    for (int j = 0; j < 16; ++j) {
        const int tc = (seg == 0) ? j : 16;
        const float4 v = *(const float4*)(wsM + (size_t)tc * 256 + i * 16 + 4 * g);
        mcs[j][0] = v.x; mcs[j][1] = v.y; mcs[j][2] = v.z; mcs[j][3] = v.w;
    }
    float kc[8], nbc[8];
    if (seg != 0) {
        const float4 k0 = *(const float4*)(wsK + (size_t)16 * 512 + i * 32 + 8 * g);
        const float4 k1 = *(const float4*)(wsK + (size_t)16 * 512 + i * 32 + 8 * g + 4);
        const float4 n0 = *(const float4*)(wsN + (size_t)16 * 128 + i * 8);
        const float4 n1 = *(const float4*)(wsN + (size_t)16 * 128 + i * 8 + 4);
        kc[0]=k0.x; kc[1]=k0.y; kc[2]=k0.z; kc[3]=k0.w;
        kc[4]=k1.x; kc[5]=k1.y; kc[6]=k1.z; kc[7]=k1.w;
        nbc[0]=n0.x; nbc[1]=n0.y; nbc[2]=n0.z; nbc[3]=n0.w;
        nbc[4]=n1.x; nbc[5]=n1.y; nbc[6]=n1.z; nbc[7]=n1.w;
    }

    float w = 0.f;
#pragma unroll
    for (int j = 0; j < 16; ++j) {
        const int t = 16 * seg + j;
        float kr[8], nbr[8];
        if (seg == 0) {
            const float4 k0 = *(const float4*)(wsK + (size_t)j * 512 + i * 32 + 8 * g);
            const float4 k1 = *(const float4*)(wsK + (size_t)j * 512 + i * 32 + 8 * g + 4);
            const float4 n0 = *(const float4*)(wsN + (size_t)j * 128 + i * 8);
            const float4 n1 = *(const float4*)(wsN + (size_t)j * 128 + i * 8 + 4);
            kr[0]=k0.x; kr[1]=k0.y; kr[2]=k0.z; kr[3]=k0.w;
            kr[4]=k1.x; kr[5]=k1.y; kr[6]=k1.z; kr[7]=k1.w;
            nbr[0]=n0.x; nbr[1]=n0.y; nbr[2]=n0.z; nbr[3]=n0.w;
            nbr[4]=n1.x; nbr[5]=n1.y; nbr[6]=n1.z; nbr[7]=n1.w;
        } else {
#pragma unroll
            for (int k = 0; k < 8; ++k) { kr[k] = kc[k]; nbr[k] = nbc[k]; }
        }
        const float a0 = a[(size_t)b * (TT * 32) + t * 32 + (lane & 31)];
        const float u0 = u[(size_t)b * (TT * 8) + t * 8 + (lane & 7)];
        float gvp = kr[0] * __shfl(a0, 8*g+0) + kr[1] * __shfl(a0, 8*g+1)
                  + kr[2] * __shfl(a0, 8*g+2) + kr[3] * __shfl(a0, 8*g+3)
                  + kr[4] * __shfl(a0, 8*g+4) + kr[5] * __shfl(a0, 8*g+5)
                  + kr[6] * __shfl(a0, 8*g+6) + kr[7] * __shfl(a0, 8*g+7);
        float nbs = nbr[0] * __shfl(u0,0) + nbr[1] * __shfl(u0,1)
                  + nbr[2] * __shfl(u0,2) + nbr[3] * __shfl(u0,3)
                  + nbr[4] * __shfl(u0,4) + nbr[5] * __shfl(u0,5)
                  + nbr[6] * __shfl(u0,6) + nbr[7] * __shfl(u0,7);
        gvp += (g == 3) ? nbs : 0.f;
        gvp += __shfl_xor(gvp, 16);
        gvp += __shfl_xor(gvp, 32);
        float part = mcs[j][0] * __shfl(w, 4*g+0) + mcs[j][1] * __shfl(w, 4*g+1)
                   + mcs[j][2] * __shfl(w, 4*g+2) + mcs[j][3] * __shfl(w, 4*g+3);
        part += __shfl_xor(part, 16);
        part += __shfl_xor(part, 32);
        w = part + gvp;
    }
    if (lane < 16) wseg[(size_t)seg * 4096 + b * 16 + i] = w;

    if (blockIdx.x == 0) {
        float pr[4];
#pragma unroll
        for (int k = 0; k < 4; ++k) pr[k] = (4 * g + k == i) ? 1.f : 0.f;
#pragma unroll
        for (int j = 0; j < 16; ++j) {
            float np[4] = {0.f, 0.f, 0.f, 0.f};
#pragma unroll
            for (int q = 0; q < 16; ++q) {
                const float mq = __shfl(mcs[j][q & 3], i + 16 * (q >> 2));
#pragma unroll
                for (int k = 0; k < 4; ++k) np[k] += mq * __shfl(pr[k], q + 16 * g);
            }
#pragma unroll
            for (int k = 0; k < 4; ++k) pr[k] = np[k];
        }
#pragma unroll
        for (int k = 0; k < 4; ++k) wsp[i * 16 + 4 * g + k] = pr[k];
    }
    if (blockIdx.x == 256) {
        float pr[4];
#pragma unroll
        for (int k = 0; k < 4; ++k) pr[k] = mcs[0][k];
#pragma unroll
        for (int r = 0; r < 4; ++r) {
            float np[4] = {0.f, 0.f, 0.f, 0.f};
#pragma unroll
            for (int q = 0; q < 16; ++q) {
                const float sq = __shfl(pr[q & 3], i + 16 * (q >> 2));
#pragma unroll
                for (int k = 0; k < 4; ++k) np[k] += sq * __shfl(pr[k], q + 16 * g);
            }
#pragma unroll
            for (int k = 0; k < 4; ++k) pr[k] = np[k];
        }
#pragma unroll
        for (int k = 0; k < 4; ++k) wsp[256 + i * 16 + 4 * g + k] = pr[k];
    }
}

// ---------------------------------------------------------------------------
// Phase C (verified R10-R12, original form) — fallback pair of phAo_k.
// ---------------------------------------------------------------------------
__global__ __launch_bounds__(64) void phCo_k(
    const float* __restrict__ u, const float* __restrict__ a,
    const float* __restrict__ wsK, const float* __restrict__ wsM,
    const float* __restrict__ wsN, const float* __restrict__ bnd,
    float* __restrict__ out)
{
    const int lane = threadIdx.x;
    const int i = lane & 15, g = lane >> 4;
    const int seg = blockIdx.x >> 8;
    const int b = blockIdx.x & 255;

    float mcs[16][4];
#pragma unroll
    for (int j = 0; j < 16; ++j) {
        const int tc = (seg == 0) ? j : 16;
        const float4 v = *(const float4*)(wsM + (size_t)tc * 256 + i * 16 + 4 * g);
        mcs[j][0] = v.x; mcs[j][1] = v.y; mcs[j][2] = v.z; mcs[j][3] = v.w;
    }
    float kc[8], nbc[8];
    if (seg != 0) {
        const float4 k0 = *(const float4*)(wsK + (size_t)16 * 512 + i * 32 + 8 * g);
        const float4 k1 = *(const float4*)(wsK + (size_t)16 * 512 + i * 32 + 8 * g + 4);
        const float4 n0 = *(const float4*)(wsN + (size_t)16 * 128 + i * 8);
        const float4 n1 = *(const float4*)(wsN + (size_t)16 * 128 + i * 8 + 4);
        kc[0]=k0.x; kc[1]=k0.y; kc[2]=k0.z; kc[3]=k0.w;
        kc[4]=k1.x; kc[5]=k1.y; kc[6]=k1.z; kc[7]=k1.w;
        nbc[0]=n0.x; nbc[1]=n0.y; nbc[2]=n0.z; nbc[3]=n0.w;
        nbc[4]=n1.x; nbc[5]=n1.y; nbc[6]=n1.z; nbc[7]=n1.w;
    }

    float mn = bnd[(size_t)seg * 4096 + b * 16 + i];
    float* ob = out + (size_t)b * 4096 + (size_t)(16 * seg) * 16;
#pragma unroll
    for (int j = 0; j < 16; ++j) {
        const int t = 16 * seg + j;
        float kr[8], nbr[8];
        if (seg == 0) {
            const float4 k0 = *(const float4*)(wsK + (size_t)j * 512 + i * 32 + 8 * g);
            const float4 k1 = *(const float4*)(wsK + (size_t)j * 512 + i * 32 + 8 * g + 4);
            const float4 n0 = *(const float4*)(wsN + (size_t)j * 128 + i * 8);
            const float4 n1 = *(const float4*)(wsN + (size_t)j * 128 + i * 8 + 4);
            kr[0]=k0.x; kr[1]=k0.y; kr[2]=k0.z; kr[3]=k0.w;
            kr[4]=k1.x; kr[5]=k1.y; kr[6]=k1.z; kr[7]=k1.w;
            nbr[0]=n0.x; nbr[1]=n0.y; nbr[2]=n0.z; nbr[3]=n0.w;
            nbr[4]=n1.x; nbr[5]=n1.y; nbr[6]=n1.z; nbr[7]=n1.w;
        } else {
#pragma unroll
            for (int k = 0; k < 8; ++k) { kr[k] = kc[k]; nbr[k] = nbc[k]; }
        }
        const float a0 = a[(size_t)b * (TT * 32) + t * 32 + (lane & 31)];
        const float u0 = u[(size_t)b * (TT * 8) + t * 8 + (lane & 7)];
        float gvp = kr[0] * __shfl(a0, 8*g+0) + kr[1] * __shfl(a0, 8*g+1)
                  + kr[2] * __shfl(a0, 8*g+2) + kr[3] * __shfl(a0, 8*g+3)
                  + kr[4] * __shfl(a0, 8*g+4) + kr[5] * __shfl(a0, 8*g+5)
                  + kr[6] * __shfl(a0, 8*g+6) + kr[7] * __shfl(a0, 8*g+7);
        float nbs = nbr[0] * __shfl(u0,0) + nbr[1] * __shfl(u0,1)
                  + nbr[2] * __shfl(u0,2) + nbr[3] * __shfl(u0,3)
                  + nbr[4] * __shfl(u0,4) + nbr[5] * __shfl(u0,5)
                  + nbr[6] * __shfl(u0,6) + nbr[7] * __shfl(u0,7);
        gvp += (g == 3) ? nbs : 0.f;
        gvp += __shfl_xor(gvp, 16);
        gvp += __shfl_xor(gvp, 32);
        float part = mcs[j][0] * __shfl(mn, 4*g+0) + mcs[j][1] * __shfl(mn, 4*g+1)
                   + mcs[j][2] * __shfl(mn, 4*g+2) + mcs[j][3] * __shfl(mn, 4*g+3);
        part += __shfl_xor(part, 16);
        part += __shfl_xor(part, 32);
        mn = part + gvp;
        if (lane < 16) ob[j * 16 + i] = mn;
    }
}

// ---------------------------------------------------------------------------
// Fallback (verified R6/R8/R9, unchanged): serial mean pass if ws too small.
// ---------------------------------------------------------------------------
__global__ __launch_bounds__(64) void meanf_k(
    const float* __restrict__ mean0, const float* __restrict__ u,
    const float* __restrict__ a, const float* __restrict__ wsK,
    const float* __restrict__ wsM, const float* __restrict__ wsN,
    float* __restrict__ out)
{
    const int lane = threadIdx.x;
    const int b = blockIdx.x;
    const int i = lane & 15;
    const int g = lane >> 4;

    const float* ub = u + (size_t)b * TT * 8;
    const float* ab = a + (size_t)b * TT * 32;
    float* ob = out + (size_t)b * TT * 16;

    float mn = mean0[b * 16 + i];
    float Mc[16];
    {
        const float4* p = (const float4*)(wsM + i * 16);
        float4 x0 = p[0], x1 = p[1], x2 = p[2], x3 = p[3];
        Mc[0]=x0.x; Mc[1]=x0.y; Mc[2]=x0.z; Mc[3]=x0.w;
        Mc[4]=x1.x; Mc[5]=x1.y; Mc[6]=x1.z; Mc[7]=x1.w;
        Mc[8]=x2.x; Mc[9]=x2.y; Mc[10]=x2.z; Mc[11]=x2.w;
        Mc[12]=x3.x; Mc[13]=x3.y; Mc[14]=x3.z; Mc[15]=x3.w;
    }
    float gv;
    {
        float4 k0 = *(const float4*)(wsK + i * 32 + 8 * g);
        float4 k1 = *(const float4*)(wsK + i * 32 + 8 * g + 4);
        float4 n0 = *(const float4*)(wsN + i * 8);
        float4 n1 = *(const float4*)(wsN + i * 8 + 4);
        float u0 = ub[lane & 7];
        float a0 = ab[lane & 31];
        float part = k0.x * __shfl(a0, 8*g+0) + k0.y * __shfl(a0, 8*g+1)
                   + k0.z * __shfl(a0, 8*g+2) + k0.w * __shfl(a0, 8*g+3)
                   + k1.x * __shfl(a0, 8*g+4) + k1.y * __shfl(a0, 8*g+5)
                   + k1.z * __shfl(a0, 8*g+6) + k1.w * __shfl(a0, 8*g+7);
        float nbs = n0.x * __shfl(u0,0) + n0.y * __shfl(u0,1)
                  + n0.z * __shfl(u0,2) + n0.w * __shfl(u0,3)
                  + n1.x * __shfl(u0,4) + n1.y * __shfl(u0,5)
                  + n1.z * __shfl(u0,6) + n1.w * __shfl(u0,7);
        part += (g == 3) ? nbs : 0.f;
        part += __shfl_xor(part, 16);
        part += __shfl_xor(part, 32);
        gv = part;
    }
    float4 mA, mB, mC, mD, kp0, kp1, np0, np1;
    float upn, apn;
    {
        const float4* p = (const float4*)(wsM + 256 + i * 16);
        mA = p[0]; mB = p[1]; mC = p[2]; mD = p[3];
        kp0 = *(const float4*)(wsK + 512 + i * 32 + 8 * g);
        kp1 = *(const float4*)(wsK + 512 + i * 32 + 8 * g + 4);
        np0 = *(const float4*)(wsN + 128 + i * 8);
        np1 = *(const float4*)(wsN + 128 + i * 8 + 4);
        upn = ub[8 + (lane & 7)];
        apn = ab[32 + (lane & 31)];
    }

    for (int t = 0; t < TT; ++t) {
        const int t2 = (t + 2 < TT) ? t + 2 : TT - 1;
        const int s2 = (t2 < WARM) ? t2 : WARM;
        const float4* mp = (const float4*)(wsM + (size_t)s2 * 256 + i * 16);
        float4 l0 = mp[0], l1 = mp[1], l2 = mp[2], l3 = mp[3];
        float4 kl0 = *(const float4*)(wsK + (size_t)s2 * 512 + i * 32 + 8 * g);
        float4 kl1 = *(const float4*)(wsK + (size_t)s2 * 512 + i * 32 + 8 * g + 4);
        float4 nl0 = *(const float4*)(wsN + (size_t)s2 * 128 + i * 8);
        float4 nl1 = *(const float4*)(wsN + (size_t)s2 * 128 + i * 8 + 4);
        float ul = ub[t2 * 8 + (lane & 7)];
        float al = ab[t2 * 32 + (lane & 31)];

        float s0 = gv, s1 = 0.f, s2f = 0.f, s3 = 0.f;
#pragma unroll
        for (int q = 0; q < 16; q += 4) {
            s0  += Mc[q]     * __shfl(mn, q);
            s1  += Mc[q + 1] * __shfl(mn, q + 1);
            s2f += Mc[q + 2] * __shfl(mn, q + 2);
            s3  += Mc[q + 3] * __shfl(mn, q + 3);
        }
        mn = (s0 + s1) + (s2f + s3);
        if (lane < 16) ob[t * 16 + lane] = mn;

        float part = kp0.x * __shfl(apn, 8*g+0) + kp0.y * __shfl(apn, 8*g+1)
                   + kp0.z * __shfl(apn, 8*g+2) + kp0.w * __shfl(apn, 8*g+3)
                   + kp1.x * __shfl(apn, 8*g+4) + kp1.y * __shfl(apn, 8*g+5)
                   + kp1.z * __shfl(apn, 8*g+6) + kp1.w * __shfl(apn, 8*g+7);
        float nbs = np0.x * __shfl(upn,0) + np0.y * __shfl(upn,1)
                  + np0.z * __shfl(upn,2) + np0.w * __shfl(upn,3)
                  + np1.x * __shfl(upn,4) + np1.y * __shfl(upn,5)
                  + np1.z * __shfl(upn,6) + np1.w * __shfl(upn,7);
        part += (g == 3) ? nbs : 0.f;
        part += __shfl_xor(part, 16);
        part += __shfl_xor(part, 32);
        gv = part;

        Mc[0]=mA.x; Mc[1]=mA.y; Mc[2]=mA.z; Mc[3]=mA.w;
        Mc[4]=mB.x; Mc[5]=mB.y; Mc[6]=mB.z; Mc[7]=mB.w;
        Mc[8]=mC.x; Mc[9]=mC.y; Mc[10]=mC.z; Mc[11]=mC.w;
        Mc[12]=mD.x; Mc[13]=mD.y; Mc[14]=mD.z; Mc[15]=mD.w;
        mA = l0; mB = l1; mC = l2; mD = l3;
        kp0 = kl0; kp1 = kl1; np0 = nl0; np1 = nl1;
        upn = ul; apn = al;
    }
}

extern "C" void kernel_launch(void* const* d_in, const int* in_sizes, int n_in,
                              void* d_out, int out_size, void* d_ws, size_t ws_size,
                              hipStream_t stream) {
    const float* mean0 = nullptr; const float* cov0 = nullptr;
    const float* u = nullptr;     const float* a = nullptr;
    const float* Mm = nullptr;    const float* Nm = nullptr;
    const float* dv = nullptr;    const float* Bm = nullptr;
    const float* Cm = nullptr;    const float* nxp = nullptr;
    const float* nap = nullptr;
    for (int i = 0; i < n_in; ++i) {
        const float* p = (const float*)d_in[i];
        switch (in_sizes[i]) {
            case 256 * 16:        mean0 = p; break;
            case 256 * 256:       cov0 = p; break;
            case 256 * 256 * 8:   u = p; break;
            case 256 * 256 * 32:  a = p; break;
            case 256:             if (!Mm) Mm = p; else Nm = p; break;
            case 16:              if (!dv) dv = p; else nxp = p; break;
            case 128:             Bm = p; break;
            case 512:             Cm = p; break;
            case 32:              nap = p; break;
            default: break;
        }
    }
    float* ws   = (float*)d_ws;
    float* wsK  = ws + OFF_K;
    float* wsM  = ws + OFF_MC;
    float* wsN  = ws + OFF_NB;
    float* wsp  = ws + OFF_P0;
    float* wseg = ws + OFF_WSEG;
    float* bnd  = ws + OFF_BND;
    float* gv   = ws + OFF_GV;
    float* pfx0 = ws + OFF_PFX0;
    float* pfx1 = ws + OFF_PFX1;

    chain_k<<<WARM + 1, 64, 0, stream>>>(Mm, Nm, dv, Bm, Cm, nxp, nap, cov0,
                                         wsK, wsM, wsN);
    if (ws_size >= NEED_WS3_BYTES) {
        phA_k<<<16 * 256, 64, 0, stream>>>(u, a, wsK, wsM, wsN, wseg, wsp, gv,
                                           pfx0, pfx1);
        phB_k<<<256, 64, 0, stream>>>(mean0, wsp, wseg, bnd);
        phC_k<<<16 * 256, 64, 0, stream>>>(pfx0, pfx1, gv, bnd, (float*)d_out);
    } else if (ws_size >= NEED_WS_BYTES) {
        phAo_k<<<16 * 256, 64, 0, stream>>>(u, a, wsK, wsM, wsN, wseg, wsp);
        phB_k<<<256, 64, 0, stream>>>(mean0, wsp, wseg, bnd);
        phCo_k<<<16 * 256, 64, 0, stream>>>(u, a, wsK, wsM, wsN, bnd, (float*)d_out);
    } else {
        meanf_k<<<256, 64, 0, stream>>>(mean0, u, a, wsK, wsM, wsN, (float*)d_out);
    }
}